// Round 16
// baseline (188.672 us; speedup 1.0000x reference)
//
#include <hip/hip_runtime.h>
#include <stdint.h>

// B=8, C=128, N=4096 (64x64), GROUPS=8 (16 ch/group)
// R22 = R21 + two independent changes:
//  (1) k_qkv: 32-n tiles -> 1024 blocks = 4 blocks/CU (was 64-n, 512 blocks,
//      2/CU). The 99us non-attn gap (k_pre+k_qkv, roofline ~15us) points at
//      k_qkv's latency-bound serial phase chain with too little TLP.
//  (2) k_attn: s_setprio(1) around QK and PV MFMA clusters (T5). With barrier
//      B deleted (R20/R21) the 8 waves run decoupled phases -> the regime
//      where setprio paid +4-7% on attn (m191); null only in lockstep (m190).
// R21 structure kept: chunk=1 fused attn+proj, in-register P, acc[4] full-C,
// one vmcnt(0)-only barrier/iter, gload_lds dbuf, b=blockIdx&7 XCD locality.

typedef __attribute__((ext_vector_type(8))) short short8;
typedef __attribute__((ext_vector_type(4))) float f32x4;
typedef __attribute__((ext_vector_type(16))) float f32x16;

#define MFMA_BF16(a, b, c) __builtin_amdgcn_mfma_f32_16x16x32_bf16((a), (b), (c), 0, 0, 0)
#define MFMA32(a, b, c) __builtin_amdgcn_mfma_f32_32x32x16_bf16((a), (b), (c), 0, 0, 0)
#define EXP2(x) __builtin_amdgcn_exp2f(x)

// (1/sqrt(128)) * log2(e) — folded into Q at k_qkv store time (softmax runs in base 2)
#define QSCALE 0.12751743f

__device__ __forceinline__ unsigned short f2bf(float f) {
    unsigned int u = __builtin_bit_cast(unsigned int, f);
    u += 0x7FFFu + ((u >> 16) & 1u);   // RNE (finite values only)
    return (unsigned short)(u >> 16);
}
__device__ __forceinline__ float bf2f(unsigned int lo16) {
    return __builtin_bit_cast(float, lo16 << 16);
}
__device__ __forceinline__ short8 ldg8(const unsigned short* p) {
    return __builtin_bit_cast(short8, *(const uint4*)p);
}
__device__ __forceinline__ unsigned int cvtpk(float lo, float hi) {
    unsigned int r;
    asm("v_cvt_pk_bf16_f32 %0, %1, %2" : "=v"(r) : "v"(lo), "v"(hi));
    return r;
}
__device__ __forceinline__ void gload16(const void* g, void* l) {
    __builtin_amdgcn_global_load_lds(
        (__attribute__((address_space(1))) void*)g,
        (__attribute__((address_space(3))) void*)l, 16, 0, 0);
}

// ---------------- Kernel 1: GroupNorm partial sums (atomic) + weight bf16 conv ------
__global__ __launch_bounds__(256) void k_pre(const float* __restrict__ x,
                                             float* __restrict__ sums,
                                             const float* __restrict__ qkv_w,
                                             const float* __restrict__ proj_w,
                                             unsigned short* __restrict__ wq,
                                             unsigned short* __restrict__ wp) {
    if (blockIdx.x >= 1024) {            // weight conversion: 64 blocks x 1024 elems
        int i = ((blockIdx.x - 1024) * 256 + threadIdx.x) * 4;
        const float* src; unsigned short* dst; int off;
        if (i < 49152) { src = qkv_w; dst = wq; off = i; }
        else           { src = proj_w; dst = wp; off = i - 49152; }
        float4 v = *(const float4*)(src + off);
        uint2 pk;
        pk.x = (unsigned int)f2bf(v.x) | ((unsigned int)f2bf(v.y) << 16);
        pk.y = (unsigned int)f2bf(v.z) | ((unsigned int)f2bf(v.w) << 16);
        *(uint2*)(dst + off) = pk;
        return;
    }
    int g     = blockIdx.x >> 4;         // 0..63 (b*8+gr); group slab contiguous
    int slice = blockIdx.x & 15;
    const float* p = x + (size_t)g * 65536 + slice * 4096;
    float s = 0.f, sq = 0.f;
#pragma unroll
    for (int i = 0; i < 4; ++i) {
        float4 v = *(const float4*)(p + threadIdx.x * 4 + i * 1024);
        s  += v.x + v.y + v.z + v.w;
        sq += v.x*v.x + v.y*v.y + v.z*v.z + v.w*v.w;
    }
#pragma unroll
    for (int m = 1; m < 64; m <<= 1) { s += __shfl_xor(s, m, 64); sq += __shfl_xor(sq, m, 64); }
    __shared__ float ss[4], ssq[4];
    int w = threadIdx.x >> 6;
    if ((threadIdx.x & 63) == 0) { ss[w] = s; ssq[w] = sq; }
    __syncthreads();
    if (threadIdx.x == 0) {
        atomicAdd(&sums[g * 2],     ss[0] + ss[1] + ss[2] + ss[3]);
        atomicAdd(&sums[g * 2 + 1], ssq[0] + ssq[1] + ssq[2] + ssq[3]);
    }
}

// ---------------- Kernel 2: fused GroupNorm-apply + QKV GEMM (32-n tiles) ----------
// 1024 blocks = (b 8) x (n-tile 128); 4 blocks/CU for latency hiding.
// Q (pre-scaled by QSCALE), K as bf16 [b][n][c]; V as bf16 [b][c][n].
__global__ __launch_bounds__(256) void k_qkv(const float* __restrict__ x,
                                             const float* __restrict__ sums,
                                             const float* __restrict__ gn_w,
                                             const float* __restrict__ gn_b,
                                             const unsigned short* __restrict__ wq,
                                             const float* __restrict__ qkv_b,
                                             unsigned short* __restrict__ q_ws,
                                             unsigned short* __restrict__ k_ws,
                                             unsigned short* __restrict__ v_ws) {
    __shared__ unsigned short h_lds[32][136];   // [n][c], +8 pad
    const int tid  = threadIdx.x;
    const int b    = blockIdx.x >> 7;
    const int n0   = (blockIdx.x & 127) << 5;
    const int lane = tid & 63, wave = tid >> 6;
    const int l15  = lane & 15, q4 = lane >> 4;

    // normalize x tile -> bf16 -> h_lds[n][c]: thread (cb=tid>>3, nn=(tid&7)*4)
    {
        int cb = tid >> 3;            // 0..31
        int nn = (tid & 7) << 2;      // 0..28
#pragma unroll
        for (int k = 0; k < 4; ++k) {
            int c = cb + (k << 5);
            float4 v = *(const float4*)(x + ((size_t)(b * 128 + c) << 12) + n0 + nn);
            int g = c >> 4;
            float ts = sums[(b * 8 + g) * 2];
            float tq = sums[(b * 8 + g) * 2 + 1];
            float mean = ts * (1.f / 65536.f);
            float var  = tq * (1.f / 65536.f) - mean * mean;
            float rstd = rsqrtf(var + 1e-5f);
            float ga = gn_w[c] * rstd;
            float be = gn_b[c] - mean * ga;
            h_lds[nn + 0][c] = f2bf(v.x * ga + be);
            h_lds[nn + 1][c] = f2bf(v.y * ga + be);
            h_lds[nn + 2][c] = f2bf(v.z * ga + be);
            h_lds[nn + 3][c] = f2bf(v.w * ga + be);
        }
    }
    __syncthreads();

    short8 bfrag[2][4];               // h[n][c]: as B (k=c, n=l15) or as A (m=n, k=c)
#pragma unroll
    for (int nt = 0; nt < 2; ++nt)
#pragma unroll
        for (int ks = 0; ks < 4; ++ks)
            bfrag[nt][ks] = *(const short8*)&h_lds[nt * 16 + l15][ks * 32 + q4 * 8];

#pragma unroll
    for (int ot = 0; ot < 6; ++ot) {
        int o0 = wave * 96 + ot * 16;                 // 16-row tile is purely Q, K, or V
        short8 af[4];                                 // w[o][c]: as A (m=o) or as B (n=o)
#pragma unroll
        for (int ks = 0; ks < 4; ++ks)
            af[ks] = ldg8(wq + (size_t)(o0 + l15) * 128 + ks * 32 + q4 * 8);

        if (o0 < 256) {               // Q or K: D[row=o(reg)][col=n=l15] -> [n][c] layout
            float bias[4];
#pragma unroll
            for (int r = 0; r < 4; ++r) bias[r] = qkv_b[o0 + q4 * 4 + r];
            float qs = (o0 < 128) ? QSCALE : 1.0f;
#pragma unroll
            for (int nt = 0; nt < 2; ++nt) {
                f32x4 acc = {0.f, 0.f, 0.f, 0.f};
#pragma unroll
                for (int ks = 0; ks < 4; ++ks)
                    acc = MFMA_BF16(af[ks], bfrag[nt][ks], acc);
                int n = n0 + nt * 16 + l15;
                unsigned short* dst = (o0 < 128) ? q_ws : k_ws;
                int oo = (o0 < 128) ? o0 : (o0 - 128);
                unsigned int lo = (unsigned int)f2bf((acc[0] + bias[0]) * qs) |
                                  ((unsigned int)f2bf((acc[1] + bias[1]) * qs) << 16);
                unsigned int hi = (unsigned int)f2bf((acc[2] + bias[2]) * qs) |
                                  ((unsigned int)f2bf((acc[3] + bias[3]) * qs) << 16);
                uint2 pk; pk.x = lo; pk.y = hi;
                *(uint2*)&dst[((size_t)(b * 4096 + n) << 7) + oo + q4 * 4] = pk;
            }
        } else {                      // V transposed: D[row=n(reg)][col=c=l15] -> [c][n]
            int c = o0 - 256 + l15;
            float vb = qkv_b[o0 + l15];
            unsigned short* vrow = v_ws + ((size_t)(b * 128 + c) << 12) + n0;
#pragma unroll
            for (int nt = 0; nt < 2; ++nt) {
                f32x4 acc = {0.f, 0.f, 0.f, 0.f};
#pragma unroll
                for (int ks = 0; ks < 4; ++ks)
                    acc = MFMA_BF16(bfrag[nt][ks], af[ks], acc);
                // n = nt*16 + q4*4 + r (4 consecutive) at fixed c -> packed 8B store
                unsigned int lo = (unsigned int)f2bf(acc[0] + vb) |
                                  ((unsigned int)f2bf(acc[1] + vb) << 16);
                unsigned int hi = (unsigned int)f2bf(acc[2] + vb) |
                                  ((unsigned int)f2bf(acc[3] + vb) << 16);
                uint2 pk; pk.x = lo; pk.y = hi;
                *(uint2*)&vrow[nt * 16 + q4 * 4] = pk;
            }
        }
    }
}

// ---------------- Kernel 3: FUSED flash attention + proj + residual ----------------
// grid = 256 blocks (b = blockIdx&7 -> batch-per-XCD L2 locality), 512 threads.
// Each block: one 128-row i-tile, ALL 4096 j (64 iters, dbuf). Main loop = R20
// + setprio(1) around the QK and PV MFMA clusters (T5: decoupled-phase regime).
__global__ __launch_bounds__(512, 2) void k_attn(const unsigned short* __restrict__ q_ws,
                                                 const unsigned short* __restrict__ k_ws,
                                                 const unsigned short* __restrict__ v_ws,
                                                 const float* __restrict__ x,
                                                 const unsigned short* __restrict__ wp,
                                                 const float* __restrict__ proj_b,
                                                 float* __restrict__ out) {
    __shared__ unsigned short K0[64][128];      // 16 KB
    __shared__ unsigned short K1[64][128];      // 16 KB
    __shared__ unsigned short V0[128][64];      // 16 KB
    __shared__ unsigned short V1[128][64];      // 16 KB
    __shared__ unsigned short O_lds[128][136];  // 34 KB  (proj input, +8 pad)
    __shared__ float Lp[256];                   // 1 KB   -> ~99 KiB total

    const int tid   = threadIdx.x;              // 0..511
    const int b     = blockIdx.x & 7;           // batch -> same XCD for same b
    const int tile  = blockIdx.x >> 3;          // 0..31
    const int i0    = tile << 7;                // 128-row i-tile
    const int lane  = tid & 63, wave = tid >> 6;
    const int ih    = wave >> 1, jh = wave & 1;
    const int l31   = lane & 31, h = lane >> 5;

    // Q frags (pre-scaled by QSCALE): lane holds i = ih*32+l31, k=c=ks*16+h*8+e
    short8 qf[8];
    {
        const unsigned short* qp =
            q_ws + ((size_t)(b * 4096 + i0 + ih * 32 + l31) << 7) + h * 8;
#pragma unroll
        for (int ks = 0; ks < 8; ++ks) qf[ks] = ldg8(qp + ks * 16);
    }

    f32x16 acc[4];                           // O[i(reg)][c = ct*32 + l31], FULL C
#pragma unroll
    for (int ct = 0; ct < 4; ++ct)
#pragma unroll
        for (int e = 0; e < 16; ++e) acc[ct][e] = 0.f;
    float l_run = 0.f;

    // K staging: chunk c = q*512 + tid; dest linear; src slot = (c&15)^(row&15)
    const unsigned short* kbase = k_ws + ((size_t)b << 19);
    int ksrc[2];
#pragma unroll
    for (int q = 0; q < 2; ++q) {
        int c   = q * 512 + tid;
        int row = c >> 4;
        ksrc[q] = row * 16 + ((c & 15) ^ (row & 15));
    }
    // V staging: chunk c = q*512 + tid; row = c>>3 = q*64 + (tid>>3);
    // src s8 = (c&7) ^ key(row), key(row) = ((tid>>3)&7) ^ wave
    const unsigned short* vlane = v_ws + ((size_t)b << 19) +
        ((size_t)(tid >> 3) << 12) +
        ((((tid & 7) ^ ((tid >> 3) & 7) ^ wave)) << 3);

#define STAGE(T, KD, VD)                                                              \
  do {                                                                                \
    _Pragma("unroll")                                                                 \
    for (int q = 0; q < 2; ++q)                                                       \
      gload16(kbase + (size_t)(T) * 8192 + ksrc[q] * 8,                               \
              (char*)(&KD[0][0]) + q * 8192 + wave * 1024);                           \
    _Pragma("unroll")                                                                 \
    for (int q = 0; q < 2; ++q)                                                       \
      gload16(vlane + (size_t)q * 262144 + (T) * 64,                                  \
              (char*)(&VD[0][0]) + q * 8192 + wave * 1024);                           \
  } while (0)

// BAR_A: buf(t) DMA (issued 1 iter ago) visible -> vmcnt(0) only; prior LDS
// reads were consumed by MFMAs (WAR safe). sched_barrier: rule #18.
#define BAR_A()                                                                       \
  do {                                                                                \
    asm volatile("s_waitcnt vmcnt(0)" ::: "memory");                                  \
    __builtin_amdgcn_s_barrier();                                                     \
    __builtin_amdgcn_sched_barrier(0);                                                \
  } while (0)

    const int krow = jh * 32 + l31;
    const int ksw  = l31 & 15;                    // krow & 15
    const int vk   = (l31 & 7) ^ (l31 >> 3);      // V key base (^ ((ct&1)<<2) per ct)
    const int irow = ih * 32 + l31;

    // prologue: prefetch tile 0 -> buf0 (drained at first BAR_A)
    STAGE(0, K0, V0);

#define ATTN_ITER(IT, KR, VR, KP, VP)                                                 \
  do {                                                                                \
    BAR_A(); /* buf visible; all waves' LDS reads consumed */                         \
    if ((IT) < 63) STAGE((IT) + 1, KP, VP);   /* in flight until next BAR_A */        \
    f32x16 s; /* S^T quadrant: row j=(r&3)+8(r>>2)+4h (+jh*32), col i (lane) */       \
    _Pragma("unroll")                                                                 \
    for (int e = 0; e < 16; ++e) s[e] = 0.f;                                          \
    __builtin_amdgcn_s_setprio(1);                                                    \
    _Pragma("unroll")                                                                 \
    for (int ks = 0; ks < 8; ++ks) {                                                  \
      short8 kf = *(const short8*)&KR[krow][((ks * 2 + h) ^ ksw) << 3];               \
      s = MFMA32(kf, qf[ks], s);                                                      \
    }                                                                                 \
    __builtin_amdgcn_s_setprio(0);                                                    \
    float pvv[16]; /* max-free base-2 softmax, in registers */                        \
    _Pragma("unroll")                                                                 \
    for (int e = 0; e < 16; ++e) pvv[e] = EXP2(fminf(s[e], 30.f));                    \
    l_run += (((pvv[0] + pvv[1]) + (pvv[2] + pvv[3])) +                               \
              ((pvv[4] + pvv[5]) + (pvv[6] + pvv[7]))) +                              \
             (((pvv[8] + pvv[9]) + (pvv[10] + pvv[11])) +                             \
              ((pvv[12] + pvv[13]) + (pvv[14] + pvv[15])));                           \
    short8 paf[2]; /* PV A-frag: lane m=i, k = j(in-quadrant) = ks*16 + h*8 + e */    \
    _Pragma("unroll")                                                                 \
    for (int ks = 0; ks < 2; ++ks) {                                                  \
      const float* pp = pvv + ks * 8;                                                 \
      unsigned int Wa = cvtpk(pp[0], pp[1]);                                          \
      unsigned int Wc = cvtpk(pp[2], pp[3]);                                          \
      unsigned int Wb = cvtpk(pp[4], pp[5]);                                          \
      unsigned int Wd = cvtpk(pp[6], pp[7]);                                          \
      auto r1 = __builtin_amdgcn_permlane32_swap(Wa, Wb, false, false);               \
      auto r2 = __builtin_amdgcn_permlane32_swap(Wc, Wd, false, false);               \
      uint4 aw; aw.x = r1[0]; aw.y = r2[0]; aw.z = r1[1]; aw.w = r2[1];               \
      paf[ks] = __builtin_bit_cast(short8, aw);   /* verified R2/R11/R20 */           \
    }                                                                                 \
    __builtin_amdgcn_s_setprio(1);                                                    \
    _Pragma("unroll")                                                                 \
    for (int ks = 0; ks < 2; ++ks)                                                    \
      _Pragma("unroll")                                                               \
      for (int ct = 0; ct < 4; ++ct) {                                                \
        short8 vf = *(const short8*)&VR[ct * 32 + l31]                                \
            [((jh * 4 + ks * 2 + h) ^ vk ^ ((ct & 1) << 2)) << 3];                    \
        acc[ct] = MFMA32(paf[ks], vf, acc[ct]);                                       \
      }                                                                               \
    __builtin_amdgcn_s_setprio(0);                                                    \
  } while (0)

    for (int ib = 0; ib < 32; ++ib) {
        int it = ib * 2;
        ATTN_ITER(it,     K0, V0, K1, V1);
        ATTN_ITER(it + 1, K1, V1, K0, V0);
    }
#undef ATTN_ITER
#undef STAGE
#undef BAR_A

    // ---- epilogue 1: jh-pair O reduce (overlay deposit in K/V bufs, f32) ----
    __syncthreads();                                 // full drain before overlay
    float l2 = l_run + __shfl_xor(l_run, 32);        // h-halves: disjoint j, same i
    if (h == 0) Lp[jh * 128 + irow] = l2;
    float* ObLow  = (ih < 2) ? (float*)&K0[0][0] : (float*)&K1[0][0];
    float* ObHigh = (ih < 2) ? (float*)&V0[0][0] : (float*)&V1[0][0];
    const int vbase = (ih & 1) * 32;                 // row offset within half-array
    if (jh) {                                        // deposit LOW c (acc[0,1])
#pragma unroll
        for (int cc = 0; cc < 2; ++cc)
#pragma unroll
            for (int r = 0; r < 16; ++r) {
                int il = (r & 3) + ((r >> 2) << 3) + (h << 2);
                ObLow[(vbase + il) * 64 + cc * 32 + l31] = (cc == 0) ? acc[0][r] : acc[1][r];
            }
    } else {                                         // deposit HIGH c (acc[2,3])
#pragma unroll
        for (int cc = 0; cc < 2; ++cc)
#pragma unroll
            for (int r = 0; r < 16; ++r) {
                int il = (r & 3) + ((r >> 2) << 3) + (h << 2);
                ObHigh[(vbase + il) * 64 + cc * 32 + l31] = (cc == 0) ? acc[2][r] : acc[3][r];
            }
    }
    __syncthreads();
    // ---- epilogue 2: normalize + write bf16 O to O_lds ----
    {
        float rl[16];
#pragma unroll
        for (int r = 0; r < 16; ++r) {
            int il = (r & 3) + ((r >> 2) << 3) + (h << 2);
            rl[r] = 1.0f / (Lp[ih * 32 + il] + Lp[128 + ih * 32 + il]);
        }
        if (jh) {                                    // finalize HIGH c: own acc[2,3]+ObHigh
#pragma unroll
            for (int cc = 0; cc < 2; ++cc)
#pragma unroll
                for (int r = 0; r < 16; ++r) {
                    int il = (r & 3) + ((r >> 2) << 3) + (h << 2);
                    float own = (cc == 0) ? acc[2][r] : acc[3][r];
                    float v = own + ObHigh[(vbase + il) * 64 + cc * 32 + l31];
                    O_lds[ih * 32 + il][64 + cc * 32 + l31] = f2bf(v * rl[r]);
                }
        } else {                                     // finalize LOW c: own acc[0,1]+ObLow
#pragma unroll
            for (int cc = 0; cc < 2; ++cc)
#pragma unroll
                for (int r = 0; r < 16; ++r) {
                    int il = (r & 3) + ((r >> 2) << 3) + (h << 2);
                    float own = (cc == 0) ? acc[0][r] : acc[1][r];
                    float v = own + ObLow[(vbase + il) * 64 + cc * 32 + l31];
                    O_lds[ih * 32 + il][cc * 32 + l31] = f2bf(v * rl[r]);
                }
        }
    }
    __syncthreads();

    // ---- epilogue 3: proj GEMM + bias + residual (k_merge_proj pattern) ----
    // out[o][n] = sum_c proj_w[o][c] * O[n][c] + proj_b[o] + x[o][n]
    {
        const int l15 = lane & 15, q4 = lane >> 4;
        int o0 = wave * 16;                          // 8 waves x 16 o-rows = 128
        short8 af[4];
#pragma unroll
        for (int ks = 0; ks < 4; ++ks)
            af[ks] = ldg8(wp + (size_t)(o0 + l15) * 128 + ks * 32 + q4 * 8);
        float pb[4];
#pragma unroll
        for (int r = 0; r < 4; ++r) pb[r] = proj_b[o0 + q4 * 4 + r];

#pragma unroll
        for (int nt = 0; nt < 8; ++nt) {             // 8 x 16 = 128 n-rows
            f32x4 pacc = {0.f, 0.f, 0.f, 0.f};
#pragma unroll
            for (int ks = 0; ks < 4; ++ks) {
                short8 bf = *(const short8*)&O_lds[nt * 16 + l15][ks * 32 + q4 * 8];
                pacc = MFMA_BF16(af[ks], bf, pacc);
            }
#pragma unroll
            for (int r = 0; r < 4; ++r) {
                size_t idx = ((size_t)(b * 128 + o0 + q4 * 4 + r) << 12) +
                             i0 + nt * 16 + l15;
                out[idx] = x[idx] + pacc[r] + pb[r];
            }
        }
    }
}

// ---------------- launch ----------------
extern "C" void kernel_launch(void* const* d_in, const int* in_sizes, int n_in,
                              void* d_out, int out_size, void* d_ws, size_t ws_size,
                              hipStream_t stream) {
    const float* x      = (const float*)d_in[0];
    const float* gn_w   = (const float*)d_in[1];
    const float* gn_b   = (const float*)d_in[2];
    const float* qkv_w  = (const float*)d_in[3];
    const float* qkv_b  = (const float*)d_in[4];
    const float* proj_w = (const float*)d_in[5];
    const float* proj_b = (const float*)d_in[6];
    float* out = (float*)d_out;

    char* ws = (char*)d_ws;
    float* sums           = (float*)ws;                              // 512 B (zeroed below)
    unsigned short* wq    = (unsigned short*)(ws + 4096);            // 96 KB
    unsigned short* wp    = (unsigned short*)(ws + 4096 + 98304);    // 32 KB
    unsigned short* q_ws  = (unsigned short*)(ws + ((size_t)1  << 20));  // 8 MB
    unsigned short* k_ws  = (unsigned short*)(ws + ((size_t)9  << 20));  // 8 MB
    unsigned short* v_ws  = (unsigned short*)(ws + ((size_t)17 << 20));  // 8 MB

    hipMemsetAsync(sums, 0, 512, stream);
    k_pre<<<1088, 256, 0, stream>>>(x, sums, qkv_w, proj_w, wq, wp);
    k_qkv<<<1024, 256, 0, stream>>>(x, sums, gn_w, gn_b, wq, qkv_b, q_ws, k_ws, v_ws);
    k_attn<<<256, 512, 0, stream>>>(q_ws, k_ws, v_ws, x, wp, proj_b, out);
}

// Round 17
// 181.957 us; speedup vs baseline: 1.0369x; 1.0369x over previous
//
#include <hip/hip_runtime.h>
#include <stdint.h>

// B=8, C=128, N=4096 (64x64), GROUPS=8 (16 ch/group)
// R23 = R21's k_attn (setprio REVERTED: R22 showed -15% on this structure —
//      T5 is negative when all waves traverse the same per-iter phase chain;
//      lesson recorded, do not retry) + R22's k_qkv 32-n/1024-block retile
//      (kept: non-attn gap 99.2 -> 96.3 us, mildly positive).
// Structure: chunk=1 fused attn+proj (R21), in-register P (cvt_pk+permlane),
// acc[4] full-C, one vmcnt(0)-only barrier/iter, gload_lds dbuf,
// b=blockIdx&7 XCD locality, (512,2) bounds.

typedef __attribute__((ext_vector_type(8))) short short8;
typedef __attribute__((ext_vector_type(4))) float f32x4;
typedef __attribute__((ext_vector_type(16))) float f32x16;

#define MFMA_BF16(a, b, c) __builtin_amdgcn_mfma_f32_16x16x32_bf16((a), (b), (c), 0, 0, 0)
#define MFMA32(a, b, c) __builtin_amdgcn_mfma_f32_32x32x16_bf16((a), (b), (c), 0, 0, 0)
#define EXP2(x) __builtin_amdgcn_exp2f(x)

// (1/sqrt(128)) * log2(e) — folded into Q at k_qkv store time (softmax runs in base 2)
#define QSCALE 0.12751743f

__device__ __forceinline__ unsigned short f2bf(float f) {
    unsigned int u = __builtin_bit_cast(unsigned int, f);
    u += 0x7FFFu + ((u >> 16) & 1u);   // RNE (finite values only)
    return (unsigned short)(u >> 16);
}
__device__ __forceinline__ float bf2f(unsigned int lo16) {
    return __builtin_bit_cast(float, lo16 << 16);
}
__device__ __forceinline__ short8 ldg8(const unsigned short* p) {
    return __builtin_bit_cast(short8, *(const uint4*)p);
}
__device__ __forceinline__ unsigned int cvtpk(float lo, float hi) {
    unsigned int r;
    asm("v_cvt_pk_bf16_f32 %0, %1, %2" : "=v"(r) : "v"(lo), "v"(hi));
    return r;
}
__device__ __forceinline__ void gload16(const void* g, void* l) {
    __builtin_amdgcn_global_load_lds(
        (__attribute__((address_space(1))) void*)g,
        (__attribute__((address_space(3))) void*)l, 16, 0, 0);
}

// ---------------- Kernel 1: GroupNorm partial sums (atomic) + weight bf16 conv ------
__global__ __launch_bounds__(256) void k_pre(const float* __restrict__ x,
                                             float* __restrict__ sums,
                                             const float* __restrict__ qkv_w,
                                             const float* __restrict__ proj_w,
                                             unsigned short* __restrict__ wq,
                                             unsigned short* __restrict__ wp) {
    if (blockIdx.x >= 1024) {            // weight conversion: 64 blocks x 1024 elems
        int i = ((blockIdx.x - 1024) * 256 + threadIdx.x) * 4;
        const float* src; unsigned short* dst; int off;
        if (i < 49152) { src = qkv_w; dst = wq; off = i; }
        else           { src = proj_w; dst = wp; off = i - 49152; }
        float4 v = *(const float4*)(src + off);
        uint2 pk;
        pk.x = (unsigned int)f2bf(v.x) | ((unsigned int)f2bf(v.y) << 16);
        pk.y = (unsigned int)f2bf(v.z) | ((unsigned int)f2bf(v.w) << 16);
        *(uint2*)(dst + off) = pk;
        return;
    }
    int g     = blockIdx.x >> 4;         // 0..63 (b*8+gr); group slab contiguous
    int slice = blockIdx.x & 15;
    const float* p = x + (size_t)g * 65536 + slice * 4096;
    float s = 0.f, sq = 0.f;
#pragma unroll
    for (int i = 0; i < 4; ++i) {
        float4 v = *(const float4*)(p + threadIdx.x * 4 + i * 1024);
        s  += v.x + v.y + v.z + v.w;
        sq += v.x*v.x + v.y*v.y + v.z*v.z + v.w*v.w;
    }
#pragma unroll
    for (int m = 1; m < 64; m <<= 1) { s += __shfl_xor(s, m, 64); sq += __shfl_xor(sq, m, 64); }
    __shared__ float ss[4], ssq[4];
    int w = threadIdx.x >> 6;
    if ((threadIdx.x & 63) == 0) { ss[w] = s; ssq[w] = sq; }
    __syncthreads();
    if (threadIdx.x == 0) {
        atomicAdd(&sums[g * 2],     ss[0] + ss[1] + ss[2] + ss[3]);
        atomicAdd(&sums[g * 2 + 1], ssq[0] + ssq[1] + ssq[2] + ssq[3]);
    }
}

// ---------------- Kernel 2: fused GroupNorm-apply + QKV GEMM (32-n tiles) ----------
// 1024 blocks = (b 8) x (n-tile 128); 4 blocks/CU for latency hiding.
// Q (pre-scaled by QSCALE), K as bf16 [b][n][c]; V as bf16 [b][c][n].
__global__ __launch_bounds__(256) void k_qkv(const float* __restrict__ x,
                                             const float* __restrict__ sums,
                                             const float* __restrict__ gn_w,
                                             const float* __restrict__ gn_b,
                                             const unsigned short* __restrict__ wq,
                                             const float* __restrict__ qkv_b,
                                             unsigned short* __restrict__ q_ws,
                                             unsigned short* __restrict__ k_ws,
                                             unsigned short* __restrict__ v_ws) {
    __shared__ unsigned short h_lds[32][136];   // [n][c], +8 pad
    const int tid  = threadIdx.x;
    const int b    = blockIdx.x >> 7;
    const int n0   = (blockIdx.x & 127) << 5;
    const int lane = tid & 63, wave = tid >> 6;
    const int l15  = lane & 15, q4 = lane >> 4;

    // normalize x tile -> bf16 -> h_lds[n][c]: thread (cb=tid>>3, nn=(tid&7)*4)
    {
        int cb = tid >> 3;            // 0..31
        int nn = (tid & 7) << 2;      // 0..28
#pragma unroll
        for (int k = 0; k < 4; ++k) {
            int c = cb + (k << 5);
            float4 v = *(const float4*)(x + ((size_t)(b * 128 + c) << 12) + n0 + nn);
            int g = c >> 4;
            float ts = sums[(b * 8 + g) * 2];
            float tq = sums[(b * 8 + g) * 2 + 1];
            float mean = ts * (1.f / 65536.f);
            float var  = tq * (1.f / 65536.f) - mean * mean;
            float rstd = rsqrtf(var + 1e-5f);
            float ga = gn_w[c] * rstd;
            float be = gn_b[c] - mean * ga;
            h_lds[nn + 0][c] = f2bf(v.x * ga + be);
            h_lds[nn + 1][c] = f2bf(v.y * ga + be);
            h_lds[nn + 2][c] = f2bf(v.z * ga + be);
            h_lds[nn + 3][c] = f2bf(v.w * ga + be);
        }
    }
    __syncthreads();

    short8 bfrag[2][4];               // h[n][c]: as B (k=c, n=l15) or as A (m=n, k=c)
#pragma unroll
    for (int nt = 0; nt < 2; ++nt)
#pragma unroll
        for (int ks = 0; ks < 4; ++ks)
            bfrag[nt][ks] = *(const short8*)&h_lds[nt * 16 + l15][ks * 32 + q4 * 8];

#pragma unroll
    for (int ot = 0; ot < 6; ++ot) {
        int o0 = wave * 96 + ot * 16;                 // 16-row tile is purely Q, K, or V
        short8 af[4];                                 // w[o][c]: as A (m=o) or as B (n=o)
#pragma unroll
        for (int ks = 0; ks < 4; ++ks)
            af[ks] = ldg8(wq + (size_t)(o0 + l15) * 128 + ks * 32 + q4 * 8);

        if (o0 < 256) {               // Q or K: D[row=o(reg)][col=n=l15] -> [n][c] layout
            float bias[4];
#pragma unroll
            for (int r = 0; r < 4; ++r) bias[r] = qkv_b[o0 + q4 * 4 + r];
            float qs = (o0 < 128) ? QSCALE : 1.0f;
#pragma unroll
            for (int nt = 0; nt < 2; ++nt) {
                f32x4 acc = {0.f, 0.f, 0.f, 0.f};
#pragma unroll
                for (int ks = 0; ks < 4; ++ks)
                    acc = MFMA_BF16(af[ks], bfrag[nt][ks], acc);
                int n = n0 + nt * 16 + l15;
                unsigned short* dst = (o0 < 128) ? q_ws : k_ws;
                int oo = (o0 < 128) ? o0 : (o0 - 128);
                unsigned int lo = (unsigned int)f2bf((acc[0] + bias[0]) * qs) |
                                  ((unsigned int)f2bf((acc[1] + bias[1]) * qs) << 16);
                unsigned int hi = (unsigned int)f2bf((acc[2] + bias[2]) * qs) |
                                  ((unsigned int)f2bf((acc[3] + bias[3]) * qs) << 16);
                uint2 pk; pk.x = lo; pk.y = hi;
                *(uint2*)&dst[((size_t)(b * 4096 + n) << 7) + oo + q4 * 4] = pk;
            }
        } else {                      // V transposed: D[row=n(reg)][col=c=l15] -> [c][n]
            int c = o0 - 256 + l15;
            float vb = qkv_b[o0 + l15];
            unsigned short* vrow = v_ws + ((size_t)(b * 128 + c) << 12) + n0;
#pragma unroll
            for (int nt = 0; nt < 2; ++nt) {
                f32x4 acc = {0.f, 0.f, 0.f, 0.f};
#pragma unroll
                for (int ks = 0; ks < 4; ++ks)
                    acc = MFMA_BF16(bfrag[nt][ks], af[ks], acc);
                // n = nt*16 + q4*4 + r (4 consecutive) at fixed c -> packed 8B store
                unsigned int lo = (unsigned int)f2bf(acc[0] + vb) |
                                  ((unsigned int)f2bf(acc[1] + vb) << 16);
                unsigned int hi = (unsigned int)f2bf(acc[2] + vb) |
                                  ((unsigned int)f2bf(acc[3] + vb) << 16);
                uint2 pk; pk.x = lo; pk.y = hi;
                *(uint2*)&vrow[nt * 16 + q4 * 4] = pk;
            }
        }
    }
}

// ---------------- Kernel 3: FUSED flash attention + proj + residual ----------------
// grid = 256 blocks (b = blockIdx&7 -> batch-per-XCD L2 locality), 512 threads.
// Each block: one 128-row i-tile, ALL 4096 j (64 iters, dbuf). Main loop = R20/R21
// (NO setprio — R22 measured -15% on this structure).
__global__ __launch_bounds__(512, 2) void k_attn(const unsigned short* __restrict__ q_ws,
                                                 const unsigned short* __restrict__ k_ws,
                                                 const unsigned short* __restrict__ v_ws,
                                                 const float* __restrict__ x,
                                                 const unsigned short* __restrict__ wp,
                                                 const float* __restrict__ proj_b,
                                                 float* __restrict__ out) {
    __shared__ unsigned short K0[64][128];      // 16 KB
    __shared__ unsigned short K1[64][128];      // 16 KB
    __shared__ unsigned short V0[128][64];      // 16 KB
    __shared__ unsigned short V1[128][64];      // 16 KB
    __shared__ unsigned short O_lds[128][136];  // 34 KB  (proj input, +8 pad)
    __shared__ float Lp[256];                   // 1 KB   -> ~99 KiB total

    const int tid   = threadIdx.x;              // 0..511
    const int b     = blockIdx.x & 7;           // batch -> same XCD for same b
    const int tile  = blockIdx.x >> 3;          // 0..31
    const int i0    = tile << 7;                // 128-row i-tile
    const int lane  = tid & 63, wave = tid >> 6;
    const int ih    = wave >> 1, jh = wave & 1;
    const int l31   = lane & 31, h = lane >> 5;

    // Q frags (pre-scaled by QSCALE): lane holds i = ih*32+l31, k=c=ks*16+h*8+e
    short8 qf[8];
    {
        const unsigned short* qp =
            q_ws + ((size_t)(b * 4096 + i0 + ih * 32 + l31) << 7) + h * 8;
#pragma unroll
        for (int ks = 0; ks < 8; ++ks) qf[ks] = ldg8(qp + ks * 16);
    }

    f32x16 acc[4];                           // O[i(reg)][c = ct*32 + l31], FULL C
#pragma unroll
    for (int ct = 0; ct < 4; ++ct)
#pragma unroll
        for (int e = 0; e < 16; ++e) acc[ct][e] = 0.f;
    float l_run = 0.f;

    // K staging: chunk c = q*512 + tid; dest linear; src slot = (c&15)^(row&15)
    const unsigned short* kbase = k_ws + ((size_t)b << 19);
    int ksrc[2];
#pragma unroll
    for (int q = 0; q < 2; ++q) {
        int c   = q * 512 + tid;
        int row = c >> 4;
        ksrc[q] = row * 16 + ((c & 15) ^ (row & 15));
    }
    // V staging: chunk c = q*512 + tid; row = c>>3 = q*64 + (tid>>3);
    // src s8 = (c&7) ^ key(row), key(row) = ((tid>>3)&7) ^ wave
    const unsigned short* vlane = v_ws + ((size_t)b << 19) +
        ((size_t)(tid >> 3) << 12) +
        ((((tid & 7) ^ ((tid >> 3) & 7) ^ wave)) << 3);

#define STAGE(T, KD, VD)                                                              \
  do {                                                                                \
    _Pragma("unroll")                                                                 \
    for (int q = 0; q < 2; ++q)                                                       \
      gload16(kbase + (size_t)(T) * 8192 + ksrc[q] * 8,                               \
              (char*)(&KD[0][0]) + q * 8192 + wave * 1024);                           \
    _Pragma("unroll")                                                                 \
    for (int q = 0; q < 2; ++q)                                                       \
      gload16(vlane + (size_t)q * 262144 + (T) * 64,                                  \
              (char*)(&VD[0][0]) + q * 8192 + wave * 1024);                           \
  } while (0)

// BAR_A: buf(t) DMA (issued 1 iter ago) visible -> vmcnt(0) only; prior LDS
// reads were consumed by MFMAs (WAR safe). sched_barrier: rule #18.
#define BAR_A()                                                                       \
  do {                                                                                \
    asm volatile("s_waitcnt vmcnt(0)" ::: "memory");                                  \
    __builtin_amdgcn_s_barrier();                                                     \
    __builtin_amdgcn_sched_barrier(0);                                                \
  } while (0)

    const int krow = jh * 32 + l31;
    const int ksw  = l31 & 15;                    // krow & 15
    const int vk   = (l31 & 7) ^ (l31 >> 3);      // V key base (^ ((ct&1)<<2) per ct)
    const int irow = ih * 32 + l31;

    // prologue: prefetch tile 0 -> buf0 (drained at first BAR_A)
    STAGE(0, K0, V0);

#define ATTN_ITER(IT, KR, VR, KP, VP)                                                 \
  do {                                                                                \
    BAR_A(); /* buf visible; all waves' LDS reads consumed */                         \
    if ((IT) < 63) STAGE((IT) + 1, KP, VP);   /* in flight until next BAR_A */        \
    f32x16 s; /* S^T quadrant: row j=(r&3)+8(r>>2)+4h (+jh*32), col i (lane) */       \
    _Pragma("unroll")                                                                 \
    for (int e = 0; e < 16; ++e) s[e] = 0.f;                                          \
    _Pragma("unroll")                                                                 \
    for (int ks = 0; ks < 8; ++ks) {                                                  \
      short8 kf = *(const short8*)&KR[krow][((ks * 2 + h) ^ ksw) << 3];               \
      s = MFMA32(kf, qf[ks], s);                                                      \
    }                                                                                 \
    float pvv[16]; /* max-free base-2 softmax, in registers */                        \
    _Pragma("unroll")                                                                 \
    for (int e = 0; e < 16; ++e) pvv[e] = EXP2(fminf(s[e], 30.f));                    \
    l_run += (((pvv[0] + pvv[1]) + (pvv[2] + pvv[3])) +                               \
              ((pvv[4] + pvv[5]) + (pvv[6] + pvv[7]))) +                              \
             (((pvv[8] + pvv[9]) + (pvv[10] + pvv[11])) +                             \
              ((pvv[12] + pvv[13]) + (pvv[14] + pvv[15])));                           \
    short8 paf[2]; /* PV A-frag: lane m=i, k = j(in-quadrant) = ks*16 + h*8 + e */    \
    _Pragma("unroll")                                                                 \
    for (int ks = 0; ks < 2; ++ks) {                                                  \
      const float* pp = pvv + ks * 8;                                                 \
      unsigned int Wa = cvtpk(pp[0], pp[1]);                                          \
      unsigned int Wc = cvtpk(pp[2], pp[3]);                                          \
      unsigned int Wb = cvtpk(pp[4], pp[5]);                                          \
      unsigned int Wd = cvtpk(pp[6], pp[7]);                                          \
      auto r1 = __builtin_amdgcn_permlane32_swap(Wa, Wb, false, false);               \
      auto r2 = __builtin_amdgcn_permlane32_swap(Wc, Wd, false, false);               \
      uint4 aw; aw.x = r1[0]; aw.y = r2[0]; aw.z = r1[1]; aw.w = r2[1];               \
      paf[ks] = __builtin_bit_cast(short8, aw);   /* verified R2/R11/R20 */           \
    }                                                                                 \
    _Pragma("unroll")                                                                 \
    for (int ks = 0; ks < 2; ++ks)                                                    \
      _Pragma("unroll")                                                               \
      for (int ct = 0; ct < 4; ++ct) {                                                \
        short8 vf = *(const short8*)&VR[ct * 32 + l31]                                \
            [((jh * 4 + ks * 2 + h) ^ vk ^ ((ct & 1) << 2)) << 3];                    \
        acc[ct] = MFMA32(paf[ks], vf, acc[ct]);                                       \
      }                                                                               \
  } while (0)

    for (int ib = 0; ib < 32; ++ib) {
        int it = ib * 2;
        ATTN_ITER(it,     K0, V0, K1, V1);
        ATTN_ITER(it + 1, K1, V1, K0, V0);
    }
#undef ATTN_ITER
#undef STAGE
#undef BAR_A

    // ---- epilogue 1: jh-pair O reduce (overlay deposit in K/V bufs, f32) ----
    __syncthreads();                                 // full drain before overlay
    float l2 = l_run + __shfl_xor(l_run, 32);        // h-halves: disjoint j, same i
    if (h == 0) Lp[jh * 128 + irow] = l2;
    float* ObLow  = (ih < 2) ? (float*)&K0[0][0] : (float*)&K1[0][0];
    float* ObHigh = (ih < 2) ? (float*)&V0[0][0] : (float*)&V1[0][0];
    const int vbase = (ih & 1) * 32;                 // row offset within half-array
    if (jh) {                                        // deposit LOW c (acc[0,1])
#pragma unroll
        for (int cc = 0; cc < 2; ++cc)
#pragma unroll
            for (int r = 0; r < 16; ++r) {
                int il = (r & 3) + ((r >> 2) << 3) + (h << 2);
                ObLow[(vbase + il) * 64 + cc * 32 + l31] = (cc == 0) ? acc[0][r] : acc[1][r];
            }
    } else {                                         // deposit HIGH c (acc[2,3])
#pragma unroll
        for (int cc = 0; cc < 2; ++cc)
#pragma unroll
            for (int r = 0; r < 16; ++r) {
                int il = (r & 3) + ((r >> 2) << 3) + (h << 2);
                ObHigh[(vbase + il) * 64 + cc * 32 + l31] = (cc == 0) ? acc[2][r] : acc[3][r];
            }
    }
    __syncthreads();
    // ---- epilogue 2: normalize + write bf16 O to O_lds ----
    {
        float rl[16];
#pragma unroll
        for (int r = 0; r < 16; ++r) {
            int il = (r & 3) + ((r >> 2) << 3) + (h << 2);
            rl[r] = 1.0f / (Lp[ih * 32 + il] + Lp[128 + ih * 32 + il]);
        }
        if (jh) {                                    // finalize HIGH c: own acc[2,3]+ObHigh
#pragma unroll
            for (int cc = 0; cc < 2; ++cc)
#pragma unroll
                for (int r = 0; r < 16; ++r) {
                    int il = (r & 3) + ((r >> 2) << 3) + (h << 2);
                    float own = (cc == 0) ? acc[2][r] : acc[3][r];
                    float v = own + ObHigh[(vbase + il) * 64 + cc * 32 + l31];
                    O_lds[ih * 32 + il][64 + cc * 32 + l31] = f2bf(v * rl[r]);
                }
        } else {                                     // finalize LOW c: own acc[0,1]+ObLow
#pragma unroll
            for (int cc = 0; cc < 2; ++cc)
#pragma unroll
                for (int r = 0; r < 16; ++r) {
                    int il = (r & 3) + ((r >> 2) << 3) + (h << 2);
                    float own = (cc == 0) ? acc[0][r] : acc[1][r];
                    float v = own + ObLow[(vbase + il) * 64 + cc * 32 + l31];
                    O_lds[ih * 32 + il][cc * 32 + l31] = f2bf(v * rl[r]);
                }
        }
    }
    __syncthreads();

    // ---- epilogue 3: proj GEMM + bias + residual (k_merge_proj pattern) ----
    // out[o][n] = sum_c proj_w[o][c] * O[n][c] + proj_b[o] + x[o][n]
    {
        const int l15 = lane & 15, q4 = lane >> 4;
        int o0 = wave * 16;                          // 8 waves x 16 o-rows = 128
        short8 af[4];
#pragma unroll
        for (int ks = 0; ks < 4; ++ks)
            af[ks] = ldg8(wp + (size_t)(o0 + l15) * 128 + ks * 32 + q4 * 8);
        float pb[4];
#pragma unroll
        for (int r = 0; r < 4; ++r) pb[r] = proj_b[o0 + q4 * 4 + r];

#pragma unroll
        for (int nt = 0; nt < 8; ++nt) {             // 8 x 16 = 128 n-rows
            f32x4 pacc = {0.f, 0.f, 0.f, 0.f};
#pragma unroll
            for (int ks = 0; ks < 4; ++ks) {
                short8 bf = *(const short8*)&O_lds[nt * 16 + l15][ks * 32 + q4 * 8];
                pacc = MFMA_BF16(af[ks], bf, pacc);
            }
#pragma unroll
            for (int r = 0; r < 4; ++r) {
                size_t idx = ((size_t)(b * 128 + o0 + q4 * 4 + r) << 12) +
                             i0 + nt * 16 + l15;
                out[idx] = x[idx] + pacc[r] + pb[r];
            }
        }
    }
}

// ---------------- launch ----------------
extern "C" void kernel_launch(void* const* d_in, const int* in_sizes, int n_in,
                              void* d_out, int out_size, void* d_ws, size_t ws_size,
                              hipStream_t stream) {
    const float* x      = (const float*)d_in[0];
    const float* gn_w   = (const float*)d_in[1];
    const float* gn_b   = (const float*)d_in[2];
    const float* qkv_w  = (const float*)d_in[3];
    const float* qkv_b  = (const float*)d_in[4];
    const float* proj_w = (const float*)d_in[5];
    const float* proj_b = (const float*)d_in[6];
    float* out = (float*)d_out;

    char* ws = (char*)d_ws;
    float* sums           = (float*)ws;                              // 512 B (zeroed below)
    unsigned short* wq    = (unsigned short*)(ws + 4096);            // 96 KB
    unsigned short* wp    = (unsigned short*)(ws + 4096 + 98304);    // 32 KB
    unsigned short* q_ws  = (unsigned short*)(ws + ((size_t)1  << 20));  // 8 MB
    unsigned short* k_ws  = (unsigned short*)(ws + ((size_t)9  << 20));  // 8 MB
    unsigned short* v_ws  = (unsigned short*)(ws + ((size_t)17 << 20));  // 8 MB

    hipMemsetAsync(sums, 0, 512, stream);
    k_pre<<<1088, 256, 0, stream>>>(x, sums, qkv_w, proj_w, wq, wp);
    k_qkv<<<1024, 256, 0, stream>>>(x, sums, gn_w, gn_b, wq, qkv_b, q_ws, k_ws, v_ws);
    k_attn<<<256, 512, 0, stream>>>(q_ws, k_ws, v_ws, x, wp, proj_b, out);
}

// Round 18
// 178.000 us; speedup vs baseline: 1.0600x; 1.0222x over previous
//
#include <hip/hip_runtime.h>
#include <stdint.h>

// B=8, C=128, N=4096 (64x64), GROUPS=8 (16 ch/group)
// R24 = R23's k_attn (frozen) + non-attn overhaul probing the constant ~95us
//      non-attn region (stable across ALL structures since R9; R22's 2x-TLP
//      null says k_qkv is not latency-bound -> suspects: store throughput,
//      memset/atomics, launch overhead):
//  (1) k_qkv (back to 64-n tiles): V stores were 8B/lane at 8KB stride (8 MB
//      total). Now staged in LDS (vstage[128][72], reusing h_lds storage
//      after bfrag loads) and written in one cooperative pass: 2 threads per
//      c-row x 64B = full 128-B lines.
//  (2) k_pre: partial sums to distinct (g,slice) slots — NO atomics, NO
//      hipMemsetAsync (dispatch deleted). k_qkv reduces 16 partials once per
//      block into ms[8][2] LDS.
// sums now 8 KB -> wq/wp moved to ws+16K.

typedef __attribute__((ext_vector_type(8))) short short8;
typedef __attribute__((ext_vector_type(4))) float f32x4;
typedef __attribute__((ext_vector_type(16))) float f32x16;

#define MFMA_BF16(a, b, c) __builtin_amdgcn_mfma_f32_16x16x32_bf16((a), (b), (c), 0, 0, 0)
#define MFMA32(a, b, c) __builtin_amdgcn_mfma_f32_32x32x16_bf16((a), (b), (c), 0, 0, 0)
#define EXP2(x) __builtin_amdgcn_exp2f(x)

// (1/sqrt(128)) * log2(e) — folded into Q at k_qkv store time (softmax runs in base 2)
#define QSCALE 0.12751743f

__device__ __forceinline__ unsigned short f2bf(float f) {
    unsigned int u = __builtin_bit_cast(unsigned int, f);
    u += 0x7FFFu + ((u >> 16) & 1u);   // RNE (finite values only)
    return (unsigned short)(u >> 16);
}
__device__ __forceinline__ float bf2f(unsigned int lo16) {
    return __builtin_bit_cast(float, lo16 << 16);
}
__device__ __forceinline__ short8 ldg8(const unsigned short* p) {
    return __builtin_bit_cast(short8, *(const uint4*)p);
}
__device__ __forceinline__ unsigned int cvtpk(float lo, float hi) {
    unsigned int r;
    asm("v_cvt_pk_bf16_f32 %0, %1, %2" : "=v"(r) : "v"(lo), "v"(hi));
    return r;
}
__device__ __forceinline__ void gload16(const void* g, void* l) {
    __builtin_amdgcn_global_load_lds(
        (__attribute__((address_space(1))) void*)g,
        (__attribute__((address_space(3))) void*)l, 16, 0, 0);
}

// ---------------- Kernel 1: GroupNorm partial sums (slotted) + weight bf16 conv -----
// Sum blocks (0..1023): (g = bid>>4, slice = bid&15) -> partials to
// sums[(g*16+slice)*2 + {0,1}]. Every slot written -> no init, no atomics.
__global__ __launch_bounds__(256) void k_pre(const float* __restrict__ x,
                                             float* __restrict__ sums,
                                             const float* __restrict__ qkv_w,
                                             const float* __restrict__ proj_w,
                                             unsigned short* __restrict__ wq,
                                             unsigned short* __restrict__ wp) {
    if (blockIdx.x >= 1024) {            // weight conversion: 64 blocks x 1024 elems
        int i = ((blockIdx.x - 1024) * 256 + threadIdx.x) * 4;
        const float* src; unsigned short* dst; int off;
        if (i < 49152) { src = qkv_w; dst = wq; off = i; }
        else           { src = proj_w; dst = wp; off = i - 49152; }
        float4 v = *(const float4*)(src + off);
        uint2 pk;
        pk.x = (unsigned int)f2bf(v.x) | ((unsigned int)f2bf(v.y) << 16);
        pk.y = (unsigned int)f2bf(v.z) | ((unsigned int)f2bf(v.w) << 16);
        *(uint2*)(dst + off) = pk;
        return;
    }
    int g     = blockIdx.x >> 4;         // 0..63 (b*8+gr); group slab contiguous
    int slice = blockIdx.x & 15;
    const float* p = x + (size_t)g * 65536 + slice * 4096;
    float s = 0.f, sq = 0.f;
#pragma unroll
    for (int i = 0; i < 4; ++i) {
        float4 v = *(const float4*)(p + threadIdx.x * 4 + i * 1024);
        s  += v.x + v.y + v.z + v.w;
        sq += v.x*v.x + v.y*v.y + v.z*v.z + v.w*v.w;
    }
#pragma unroll
    for (int m = 1; m < 64; m <<= 1) { s += __shfl_xor(s, m, 64); sq += __shfl_xor(sq, m, 64); }
    __shared__ float ss[4], ssq[4];
    int w = threadIdx.x >> 6;
    if ((threadIdx.x & 63) == 0) { ss[w] = s; ssq[w] = sq; }
    __syncthreads();
    if (threadIdx.x == 0) {
        sums[(g * 16 + slice) * 2]     = ss[0] + ss[1] + ss[2] + ss[3];
        sums[(g * 16 + slice) * 2 + 1] = ssq[0] + ssq[1] + ssq[2] + ssq[3];
    }
}

// ---------------- Kernel 2: fused GroupNorm-apply + QKV GEMM (64-n tiles) ----------
// 512 blocks = (b 8) x (n-tile 64). Q (pre-scaled), K bf16 [b][n][c];
// V bf16 [b][c][n] via LDS-staged COALESCED writes (full 128-B lines).
__global__ __launch_bounds__(256) void k_qkv(const float* __restrict__ x,
                                             const float* __restrict__ sums,
                                             const float* __restrict__ gn_w,
                                             const float* __restrict__ gn_b,
                                             const unsigned short* __restrict__ wq,
                                             const float* __restrict__ qkv_b,
                                             unsigned short* __restrict__ q_ws,
                                             unsigned short* __restrict__ k_ws,
                                             unsigned short* __restrict__ v_ws) {
    __shared__ unsigned short h_lds[64][144];   // 18432 B; reused as vstage[128][72]
    __shared__ float ms[8][2];                  // per-group (mean, rstd)
    const int tid  = threadIdx.x;
    const int b    = blockIdx.x >> 6;
    const int n0   = (blockIdx.x & 63) << 6;
    const int lane = tid & 63, wave = tid >> 6;
    const int l15  = lane & 15, q4 = lane >> 4;

    if (tid < 8) {                     // reduce 16 partials per group
        float s = 0.f, q = 0.f;
        const float* sp = sums + (size_t)(b * 8 + tid) * 32;
#pragma unroll
        for (int i = 0; i < 16; ++i) { s += sp[i * 2]; q += sp[i * 2 + 1]; }
        float mean = s * (1.f / 65536.f);
        float var  = q * (1.f / 65536.f) - mean * mean;
        ms[tid][0] = mean;
        ms[tid][1] = rsqrtf(var + 1e-5f);
    }
    __syncthreads();

    // normalize x tile -> bf16 -> h_lds[n][c]
    {
        int cb = tid >> 4;            // 0..15
        int nn = (tid & 15) << 2;     // 0..60
#pragma unroll
        for (int k = 0; k < 8; ++k) {
            int c = cb + (k << 4);
            float4 v = *(const float4*)(x + ((size_t)(b * 128 + c) << 12) + n0 + nn);
            int g = c >> 4;
            float mean = ms[g][0];
            float rstd = ms[g][1];
            float ga = gn_w[c] * rstd;
            float be = gn_b[c] - mean * ga;
            h_lds[nn + 0][c] = f2bf(v.x * ga + be);
            h_lds[nn + 1][c] = f2bf(v.y * ga + be);
            h_lds[nn + 2][c] = f2bf(v.z * ga + be);
            h_lds[nn + 3][c] = f2bf(v.w * ga + be);
        }
    }
    __syncthreads();

    short8 bfrag[4][4];               // h[n][c]: as B (k=c, n=l15) or as A (m=n, k=c)
#pragma unroll
    for (int nt = 0; nt < 4; ++nt)
#pragma unroll
        for (int ks = 0; ks < 4; ++ks)
            bfrag[nt][ks] = *(const short8*)&h_lds[nt * 16 + l15][ks * 32 + q4 * 8];
    __syncthreads();                  // h_lds dead (bfrag in regs) -> vstage reuse OK

    unsigned short* vstage = &h_lds[0][0];   // [128][72] shorts (18432 B)

#pragma unroll
    for (int ot = 0; ot < 6; ++ot) {
        int o0 = wave * 96 + ot * 16;                 // 16-row tile is purely Q, K, or V
        short8 af[4];                                 // w[o][c]: as A (m=o) or as B (n=o)
#pragma unroll
        for (int ks = 0; ks < 4; ++ks)
            af[ks] = ldg8(wq + (size_t)(o0 + l15) * 128 + ks * 32 + q4 * 8);

        if (o0 < 256) {               // Q or K: D[row=o(reg)][col=n=l15] -> [n][c] layout
            float bias[4];
#pragma unroll
            for (int r = 0; r < 4; ++r) bias[r] = qkv_b[o0 + q4 * 4 + r];
            float qs = (o0 < 128) ? QSCALE : 1.0f;
#pragma unroll
            for (int nt = 0; nt < 4; ++nt) {
                f32x4 acc = {0.f, 0.f, 0.f, 0.f};
#pragma unroll
                for (int ks = 0; ks < 4; ++ks)
                    acc = MFMA_BF16(af[ks], bfrag[nt][ks], acc);
                int n = n0 + nt * 16 + l15;
                unsigned short* dst = (o0 < 128) ? q_ws : k_ws;
                int oo = (o0 < 128) ? o0 : (o0 - 128);
                unsigned int lo = (unsigned int)f2bf((acc[0] + bias[0]) * qs) |
                                  ((unsigned int)f2bf((acc[1] + bias[1]) * qs) << 16);
                unsigned int hi = (unsigned int)f2bf((acc[2] + bias[2]) * qs) |
                                  ((unsigned int)f2bf((acc[3] + bias[3]) * qs) << 16);
                uint2 pk; pk.x = lo; pk.y = hi;
                *(uint2*)&dst[((size_t)(b * 4096 + n) << 7) + oo + q4 * 4] = pk;
            }
        } else {                      // V transposed: D[row=n(reg)][col=c=l15] -> vstage
            int c = o0 - 256 + l15;
            float vb = qkv_b[o0 + l15];
#pragma unroll
            for (int nt = 0; nt < 4; ++nt) {
                f32x4 acc = {0.f, 0.f, 0.f, 0.f};
#pragma unroll
                for (int ks = 0; ks < 4; ++ks)
                    acc = MFMA_BF16(bfrag[nt][ks], af[ks], acc);
                // n-local = nt*16 + q4*4 + r (4 consecutive) at fixed c -> 8B LDS write
                unsigned int lo = (unsigned int)f2bf(acc[0] + vb) |
                                  ((unsigned int)f2bf(acc[1] + vb) << 16);
                unsigned int hi = (unsigned int)f2bf(acc[2] + vb) |
                                  ((unsigned int)f2bf(acc[3] + vb) << 16);
                uint2 pk; pk.x = lo; pk.y = hi;
                *(uint2*)&vstage[c * 72 + nt * 16 + q4 * 4] = pk;
            }
        }
    }
    __syncthreads();                  // vstage complete

    // cooperative V write: thread t -> row c = t>>1, 32-n half = t&1 -> 64 B contig;
    // thread pairs fill full 128-B lines of v_ws[b][c][n0..n0+63].
    {
        int c = tid >> 1, hf = tid & 1;
        const unsigned short* src = vstage + c * 72 + hf * 32;
        unsigned short* dst = v_ws + ((size_t)(b * 128 + c) << 12) + n0 + hf * 32;
        uint4 a0 = *(const uint4*)(src + 0);
        uint4 a1 = *(const uint4*)(src + 8);
        uint4 a2 = *(const uint4*)(src + 16);
        uint4 a3 = *(const uint4*)(src + 24);
        *(uint4*)(dst + 0)  = a0;
        *(uint4*)(dst + 8)  = a1;
        *(uint4*)(dst + 16) = a2;
        *(uint4*)(dst + 24) = a3;
    }
}

// ---------------- Kernel 3: FUSED flash attention + proj + residual ----------------
// grid = 256 blocks (b = blockIdx&7 -> batch-per-XCD L2 locality), 512 threads.
// Each block: one 128-row i-tile, ALL 4096 j (64 iters, dbuf). Main loop = R21/R23
// (NO setprio — R22 measured -15% on this structure).
__global__ __launch_bounds__(512, 2) void k_attn(const unsigned short* __restrict__ q_ws,
                                                 const unsigned short* __restrict__ k_ws,
                                                 const unsigned short* __restrict__ v_ws,
                                                 const float* __restrict__ x,
                                                 const unsigned short* __restrict__ wp,
                                                 const float* __restrict__ proj_b,
                                                 float* __restrict__ out) {
    __shared__ unsigned short K0[64][128];      // 16 KB
    __shared__ unsigned short K1[64][128];      // 16 KB
    __shared__ unsigned short V0[128][64];      // 16 KB
    __shared__ unsigned short V1[128][64];      // 16 KB
    __shared__ unsigned short O_lds[128][136];  // 34 KB  (proj input, +8 pad)
    __shared__ float Lp[256];                   // 1 KB   -> ~99 KiB total

    const int tid   = threadIdx.x;              // 0..511
    const int b     = blockIdx.x & 7;           // batch -> same XCD for same b
    const int tile  = blockIdx.x >> 3;          // 0..31
    const int i0    = tile << 7;                // 128-row i-tile
    const int lane  = tid & 63, wave = tid >> 6;
    const int ih    = wave >> 1, jh = wave & 1;
    const int l31   = lane & 31, h = lane >> 5;

    // Q frags (pre-scaled by QSCALE): lane holds i = ih*32+l31, k=c=ks*16+h*8+e
    short8 qf[8];
    {
        const unsigned short* qp =
            q_ws + ((size_t)(b * 4096 + i0 + ih * 32 + l31) << 7) + h * 8;
#pragma unroll
        for (int ks = 0; ks < 8; ++ks) qf[ks] = ldg8(qp + ks * 16);
    }

    f32x16 acc[4];                           // O[i(reg)][c = ct*32 + l31], FULL C
#pragma unroll
    for (int ct = 0; ct < 4; ++ct)
#pragma unroll
        for (int e = 0; e < 16; ++e) acc[ct][e] = 0.f;
    float l_run = 0.f;

    // K staging: chunk c = q*512 + tid; dest linear; src slot = (c&15)^(row&15)
    const unsigned short* kbase = k_ws + ((size_t)b << 19);
    int ksrc[2];
#pragma unroll
    for (int q = 0; q < 2; ++q) {
        int c   = q * 512 + tid;
        int row = c >> 4;
        ksrc[q] = row * 16 + ((c & 15) ^ (row & 15));
    }
    // V staging: chunk c = q*512 + tid; row = c>>3 = q*64 + (tid>>3);
    // src s8 = (c&7) ^ key(row), key(row) = ((tid>>3)&7) ^ wave
    const unsigned short* vlane = v_ws + ((size_t)b << 19) +
        ((size_t)(tid >> 3) << 12) +
        ((((tid & 7) ^ ((tid >> 3) & 7) ^ wave)) << 3);

#define STAGE(T, KD, VD)                                                              \
  do {                                                                                \
    _Pragma("unroll")                                                                 \
    for (int q = 0; q < 2; ++q)                                                       \
      gload16(kbase + (size_t)(T) * 8192 + ksrc[q] * 8,                               \
              (char*)(&KD[0][0]) + q * 8192 + wave * 1024);                           \
    _Pragma("unroll")                                                                 \
    for (int q = 0; q < 2; ++q)                                                       \
      gload16(vlane + (size_t)q * 262144 + (T) * 64,                                  \
              (char*)(&VD[0][0]) + q * 8192 + wave * 1024);                           \
  } while (0)

// BAR_A: buf(t) DMA (issued 1 iter ago) visible -> vmcnt(0) only; prior LDS
// reads were consumed by MFMAs (WAR safe). sched_barrier: rule #18.
#define BAR_A()                                                                       \
  do {                                                                                \
    asm volatile("s_waitcnt vmcnt(0)" ::: "memory");                                  \
    __builtin_amdgcn_s_barrier();                                                     \
    __builtin_amdgcn_sched_barrier(0);                                                \
  } while (0)

    const int krow = jh * 32 + l31;
    const int ksw  = l31 & 15;                    // krow & 15
    const int vk   = (l31 & 7) ^ (l31 >> 3);      // V key base (^ ((ct&1)<<2) per ct)
    const int irow = ih * 32 + l31;

    // prologue: prefetch tile 0 -> buf0 (drained at first BAR_A)
    STAGE(0, K0, V0);

#define ATTN_ITER(IT, KR, VR, KP, VP)                                                 \
  do {                                                                                \
    BAR_A(); /* buf visible; all waves' LDS reads consumed */                         \
    if ((IT) < 63) STAGE((IT) + 1, KP, VP);   /* in flight until next BAR_A */        \
    f32x16 s; /* S^T quadrant: row j=(r&3)+8(r>>2)+4h (+jh*32), col i (lane) */       \
    _Pragma("unroll")                                                                 \
    for (int e = 0; e < 16; ++e) s[e] = 0.f;                                          \
    _Pragma("unroll")                                                                 \
    for (int ks = 0; ks < 8; ++ks) {                                                  \
      short8 kf = *(const short8*)&KR[krow][((ks * 2 + h) ^ ksw) << 3];               \
      s = MFMA32(kf, qf[ks], s);                                                      \
    }                                                                                 \
    float pvv[16]; /* max-free base-2 softmax, in registers */                        \
    _Pragma("unroll")                                                                 \
    for (int e = 0; e < 16; ++e) pvv[e] = EXP2(fminf(s[e], 30.f));                    \
    l_run += (((pvv[0] + pvv[1]) + (pvv[2] + pvv[3])) +                               \
              ((pvv[4] + pvv[5]) + (pvv[6] + pvv[7]))) +                              \
             (((pvv[8] + pvv[9]) + (pvv[10] + pvv[11])) +                             \
              ((pvv[12] + pvv[13]) + (pvv[14] + pvv[15])));                           \
    short8 paf[2]; /* PV A-frag: lane m=i, k = j(in-quadrant) = ks*16 + h*8 + e */    \
    _Pragma("unroll")                                                                 \
    for (int ks = 0; ks < 2; ++ks) {                                                  \
      const float* pp = pvv + ks * 8;                                                 \
      unsigned int Wa = cvtpk(pp[0], pp[1]);                                          \
      unsigned int Wc = cvtpk(pp[2], pp[3]);                                          \
      unsigned int Wb = cvtpk(pp[4], pp[5]);                                          \
      unsigned int Wd = cvtpk(pp[6], pp[7]);                                          \
      auto r1 = __builtin_amdgcn_permlane32_swap(Wa, Wb, false, false);               \
      auto r2 = __builtin_amdgcn_permlane32_swap(Wc, Wd, false, false);               \
      uint4 aw; aw.x = r1[0]; aw.y = r2[0]; aw.z = r1[1]; aw.w = r2[1];               \
      paf[ks] = __builtin_bit_cast(short8, aw);   /* verified R2/R11/R20 */           \
    }                                                                                 \
    _Pragma("unroll")                                                                 \
    for (int ks = 0; ks < 2; ++ks)                                                    \
      _Pragma("unroll")                                                               \
      for (int ct = 0; ct < 4; ++ct) {                                                \
        short8 vf = *(const short8*)&VR[ct * 32 + l31]                                \
            [((jh * 4 + ks * 2 + h) ^ vk ^ ((ct & 1) << 2)) << 3];                    \
        acc[ct] = MFMA32(paf[ks], vf, acc[ct]);                                       \
      }                                                                               \
  } while (0)

    for (int ib = 0; ib < 32; ++ib) {
        int it = ib * 2;
        ATTN_ITER(it,     K0, V0, K1, V1);
        ATTN_ITER(it + 1, K1, V1, K0, V0);
    }
#undef ATTN_ITER
#undef STAGE
#undef BAR_A

    // ---- epilogue 1: jh-pair O reduce (overlay deposit in K/V bufs, f32) ----
    __syncthreads();                                 // full drain before overlay
    float l2 = l_run + __shfl_xor(l_run, 32);        // h-halves: disjoint j, same i
    if (h == 0) Lp[jh * 128 + irow] = l2;
    float* ObLow  = (ih < 2) ? (float*)&K0[0][0] : (float*)&K1[0][0];
    float* ObHigh = (ih < 2) ? (float*)&V0[0][0] : (float*)&V1[0][0];
    const int vbase = (ih & 1) * 32;                 // row offset within half-array
    if (jh) {                                        // deposit LOW c (acc[0,1])
#pragma unroll
        for (int cc = 0; cc < 2; ++cc)
#pragma unroll
            for (int r = 0; r < 16; ++r) {
                int il = (r & 3) + ((r >> 2) << 3) + (h << 2);
                ObLow[(vbase + il) * 64 + cc * 32 + l31] = (cc == 0) ? acc[0][r] : acc[1][r];
            }
    } else {                                         // deposit HIGH c (acc[2,3])
#pragma unroll
        for (int cc = 0; cc < 2; ++cc)
#pragma unroll
            for (int r = 0; r < 16; ++r) {
                int il = (r & 3) + ((r >> 2) << 3) + (h << 2);
                ObHigh[(vbase + il) * 64 + cc * 32 + l31] = (cc == 0) ? acc[2][r] : acc[3][r];
            }
    }
    __syncthreads();
    // ---- epilogue 2: normalize + write bf16 O to O_lds ----
    {
        float rl[16];
#pragma unroll
        for (int r = 0; r < 16; ++r) {
            int il = (r & 3) + ((r >> 2) << 3) + (h << 2);
            rl[r] = 1.0f / (Lp[ih * 32 + il] + Lp[128 + ih * 32 + il]);
        }
        if (jh) {                                    // finalize HIGH c: own acc[2,3]+ObHigh
#pragma unroll
            for (int cc = 0; cc < 2; ++cc)
#pragma unroll
                for (int r = 0; r < 16; ++r) {
                    int il = (r & 3) + ((r >> 2) << 3) + (h << 2);
                    float own = (cc == 0) ? acc[2][r] : acc[3][r];
                    float v = own + ObHigh[(vbase + il) * 64 + cc * 32 + l31];
                    O_lds[ih * 32 + il][64 + cc * 32 + l31] = f2bf(v * rl[r]);
                }
        } else {                                     // finalize LOW c: own acc[0,1]+ObLow
#pragma unroll
            for (int cc = 0; cc < 2; ++cc)
#pragma unroll
                for (int r = 0; r < 16; ++r) {
                    int il = (r & 3) + ((r >> 2) << 3) + (h << 2);
                    float own = (cc == 0) ? acc[0][r] : acc[1][r];
                    float v = own + ObLow[(vbase + il) * 64 + cc * 32 + l31];
                    O_lds[ih * 32 + il][cc * 32 + l31] = f2bf(v * rl[r]);
                }
        }
    }
    __syncthreads();

    // ---- epilogue 3: proj GEMM + bias + residual (k_merge_proj pattern) ----
    // out[o][n] = sum_c proj_w[o][c] * O[n][c] + proj_b[o] + x[o][n]
    {
        const int l15 = lane & 15, q4 = lane >> 4;
        int o0 = wave * 16;                          // 8 waves x 16 o-rows = 128
        short8 af[4];
#pragma unroll
        for (int ks = 0; ks < 4; ++ks)
            af[ks] = ldg8(wp + (size_t)(o0 + l15) * 128 + ks * 32 + q4 * 8);
        float pb[4];
#pragma unroll
        for (int r = 0; r < 4; ++r) pb[r] = proj_b[o0 + q4 * 4 + r];

#pragma unroll
        for (int nt = 0; nt < 8; ++nt) {             // 8 x 16 = 128 n-rows
            f32x4 pacc = {0.f, 0.f, 0.f, 0.f};
#pragma unroll
            for (int ks = 0; ks < 4; ++ks) {
                short8 bf = *(const short8*)&O_lds[nt * 16 + l15][ks * 32 + q4 * 8];
                pacc = MFMA_BF16(af[ks], bf, pacc);
            }
#pragma unroll
            for (int r = 0; r < 4; ++r) {
                size_t idx = ((size_t)(b * 128 + o0 + q4 * 4 + r) << 12) +
                             i0 + nt * 16 + l15;
                out[idx] = x[idx] + pacc[r] + pb[r];
            }
        }
    }
}

// ---------------- launch ----------------
extern "C" void kernel_launch(void* const* d_in, const int* in_sizes, int n_in,
                              void* d_out, int out_size, void* d_ws, size_t ws_size,
                              hipStream_t stream) {
    const float* x      = (const float*)d_in[0];
    const float* gn_w   = (const float*)d_in[1];
    const float* gn_b   = (const float*)d_in[2];
    const float* qkv_w  = (const float*)d_in[3];
    const float* qkv_b  = (const float*)d_in[4];
    const float* proj_w = (const float*)d_in[5];
    const float* proj_b = (const float*)d_in[6];
    float* out = (float*)d_out;

    char* ws = (char*)d_ws;
    float* sums           = (float*)ws;                              // 8 KB partials (no init needed)
    unsigned short* wq    = (unsigned short*)(ws + 16384);           // 96 KB
    unsigned short* wp    = (unsigned short*)(ws + 16384 + 98304);   // 32 KB
    unsigned short* q_ws  = (unsigned short*)(ws + ((size_t)1  << 20));  // 8 MB
    unsigned short* k_ws  = (unsigned short*)(ws + ((size_t)9  << 20));  // 8 MB
    unsigned short* v_ws  = (unsigned short*)(ws + ((size_t)17 << 20));  // 8 MB

    k_pre<<<1088, 256, 0, stream>>>(x, sums, qkv_w, proj_w, wq, wp);
    k_qkv<<<512, 256, 0, stream>>>(x, sums, gn_w, gn_b, wq, qkv_b, q_ws, k_ws, v_ws);
    k_attn<<<256, 512, 0, stream>>>(q_ws, k_ws, v_ws, x, wp, proj_b, out);
}

// Round 19
// 175.374 us; speedup vs baseline: 1.0758x; 1.0150x over previous
//
#include <hip/hip_runtime.h>
#include <stdint.h>

// B=8, C=128, N=4096 (64x64), GROUPS=8 (16 ch/group)
// R25 = R24 + Q-GEMM fused into k_attn's prologue (k_qkv slims to K/V only).
//      The ~95us non-attn gap is insensitive to k_qkv tiling (R22 null) and
//      V-store coalescing (R24 -5us); roofline says ~15us -> either invisible
//      real time or overhead. This round removes a third of k_qkv + all q_ws
//      traffic (8MB w + 8MB r) by computing Q inside k_attn:
//        prologue: sums->ms, GN(x-tile)->h in O_lds (free till epilogue),
//        Wq GEMM (verified k_qkv pattern) -> Q staged in K0/K1 (free till
//        STAGE(0)), qf loaded from LDS, then main loop byte-identical R21/R23.
//      k_pre unchanged (slotted sums, no memset/atomics).

typedef __attribute__((ext_vector_type(8))) short short8;
typedef __attribute__((ext_vector_type(4))) float f32x4;
typedef __attribute__((ext_vector_type(16))) float f32x16;

#define MFMA_BF16(a, b, c) __builtin_amdgcn_mfma_f32_16x16x32_bf16((a), (b), (c), 0, 0, 0)
#define MFMA32(a, b, c) __builtin_amdgcn_mfma_f32_32x32x16_bf16((a), (b), (c), 0, 0, 0)
#define EXP2(x) __builtin_amdgcn_exp2f(x)

// (1/sqrt(128)) * log2(e) — folded into Q at store time (softmax runs in base 2)
#define QSCALE 0.12751743f

__device__ __forceinline__ unsigned short f2bf(float f) {
    unsigned int u = __builtin_bit_cast(unsigned int, f);
    u += 0x7FFFu + ((u >> 16) & 1u);   // RNE (finite values only)
    return (unsigned short)(u >> 16);
}
__device__ __forceinline__ float bf2f(unsigned int lo16) {
    return __builtin_bit_cast(float, lo16 << 16);
}
__device__ __forceinline__ short8 ldg8(const unsigned short* p) {
    return __builtin_bit_cast(short8, *(const uint4*)p);
}
__device__ __forceinline__ unsigned int cvtpk(float lo, float hi) {
    unsigned int r;
    asm("v_cvt_pk_bf16_f32 %0, %1, %2" : "=v"(r) : "v"(lo), "v"(hi));
    return r;
}
__device__ __forceinline__ void gload16(const void* g, void* l) {
    __builtin_amdgcn_global_load_lds(
        (__attribute__((address_space(1))) void*)g,
        (__attribute__((address_space(3))) void*)l, 16, 0, 0);
}

// ---------------- Kernel 1: GroupNorm partial sums (slotted) + weight bf16 conv -----
__global__ __launch_bounds__(256) void k_pre(const float* __restrict__ x,
                                             float* __restrict__ sums,
                                             const float* __restrict__ qkv_w,
                                             const float* __restrict__ proj_w,
                                             unsigned short* __restrict__ wq,
                                             unsigned short* __restrict__ wp) {
    if (blockIdx.x >= 1024) {            // weight conversion: 64 blocks x 1024 elems
        int i = ((blockIdx.x - 1024) * 256 + threadIdx.x) * 4;
        const float* src; unsigned short* dst; int off;
        if (i < 49152) { src = qkv_w; dst = wq; off = i; }
        else           { src = proj_w; dst = wp; off = i - 49152; }
        float4 v = *(const float4*)(src + off);
        uint2 pk;
        pk.x = (unsigned int)f2bf(v.x) | ((unsigned int)f2bf(v.y) << 16);
        pk.y = (unsigned int)f2bf(v.z) | ((unsigned int)f2bf(v.w) << 16);
        *(uint2*)(dst + off) = pk;
        return;
    }
    int g     = blockIdx.x >> 4;         // 0..63 (b*8+gr); group slab contiguous
    int slice = blockIdx.x & 15;
    const float* p = x + (size_t)g * 65536 + slice * 4096;
    float s = 0.f, sq = 0.f;
#pragma unroll
    for (int i = 0; i < 4; ++i) {
        float4 v = *(const float4*)(p + threadIdx.x * 4 + i * 1024);
        s  += v.x + v.y + v.z + v.w;
        sq += v.x*v.x + v.y*v.y + v.z*v.z + v.w*v.w;
    }
#pragma unroll
    for (int m = 1; m < 64; m <<= 1) { s += __shfl_xor(s, m, 64); sq += __shfl_xor(sq, m, 64); }
    __shared__ float ss[4], ssq[4];
    int w = threadIdx.x >> 6;
    if ((threadIdx.x & 63) == 0) { ss[w] = s; ssq[w] = sq; }
    __syncthreads();
    if (threadIdx.x == 0) {
        sums[(g * 16 + slice) * 2]     = ss[0] + ss[1] + ss[2] + ss[3];
        sums[(g * 16 + slice) * 2 + 1] = ssq[0] + ssq[1] + ssq[2] + ssq[3];
    }
}

// ---------------- Kernel 2: fused GroupNorm-apply + K/V GEMM (64-n tiles) ----------
// 512 blocks = (b 8) x (n-tile 64). K bf16 [b][n][c]; V bf16 [b][c][n] via
// LDS-staged coalesced writes. Q is produced inside k_attn (R25).
__global__ __launch_bounds__(256) void k_qkv(const float* __restrict__ x,
                                             const float* __restrict__ sums,
                                             const float* __restrict__ gn_w,
                                             const float* __restrict__ gn_b,
                                             const unsigned short* __restrict__ wq,
                                             const float* __restrict__ qkv_b,
                                             unsigned short* __restrict__ k_ws,
                                             unsigned short* __restrict__ v_ws) {
    __shared__ unsigned short h_lds[64][144];   // 18432 B; reused as vstage[128][72]
    __shared__ float ms[8][2];                  // per-group (mean, rstd)
    const int tid  = threadIdx.x;
    const int b    = blockIdx.x >> 6;
    const int n0   = (blockIdx.x & 63) << 6;
    const int lane = tid & 63, wave = tid >> 6;
    const int l15  = lane & 15, q4 = lane >> 4;

    if (tid < 8) {                     // reduce 16 partials per group
        float s = 0.f, q = 0.f;
        const float* sp = sums + (size_t)(b * 8 + tid) * 32;
#pragma unroll
        for (int i = 0; i < 16; ++i) { s += sp[i * 2]; q += sp[i * 2 + 1]; }
        float mean = s * (1.f / 65536.f);
        float var  = q * (1.f / 65536.f) - mean * mean;
        ms[tid][0] = mean;
        ms[tid][1] = rsqrtf(var + 1e-5f);
    }
    __syncthreads();

    // normalize x tile -> bf16 -> h_lds[n][c]
    {
        int cb = tid >> 4;            // 0..15
        int nn = (tid & 15) << 2;     // 0..60
#pragma unroll
        for (int k = 0; k < 8; ++k) {
            int c = cb + (k << 4);
            float4 v = *(const float4*)(x + ((size_t)(b * 128 + c) << 12) + n0 + nn);
            int g = c >> 4;
            float mean = ms[g][0];
            float rstd = ms[g][1];
            float ga = gn_w[c] * rstd;
            float be = gn_b[c] - mean * ga;
            h_lds[nn + 0][c] = f2bf(v.x * ga + be);
            h_lds[nn + 1][c] = f2bf(v.y * ga + be);
            h_lds[nn + 2][c] = f2bf(v.z * ga + be);
            h_lds[nn + 3][c] = f2bf(v.w * ga + be);
        }
    }
    __syncthreads();

    short8 bfrag[4][4];               // h[n][c]: as B (k=c, n=l15) or as A (m=n, k=c)
#pragma unroll
    for (int nt = 0; nt < 4; ++nt)
#pragma unroll
        for (int ks = 0; ks < 4; ++ks)
            bfrag[nt][ks] = *(const short8*)&h_lds[nt * 16 + l15][ks * 32 + q4 * 8];
    __syncthreads();                  // h_lds dead (bfrag in regs) -> vstage reuse OK

    unsigned short* vstage = &h_lds[0][0];   // [128][72] shorts (18432 B)

#pragma unroll
    for (int ot = 0; ot < 4; ++ot) {
        int o0 = wave * 64 + ot * 16;                 // local K/V output row (0..255)
        short8 af[4];                                 // w[128+o0..][c]
#pragma unroll
        for (int ks = 0; ks < 4; ++ks)
            af[ks] = ldg8(wq + (size_t)(128 + o0 + l15) * 128 + ks * 32 + q4 * 8);

        if (o0 < 128) {               // K: D[row=o(reg)][col=n=l15] -> [n][c] layout
            float bias[4];
#pragma unroll
            for (int r = 0; r < 4; ++r) bias[r] = qkv_b[128 + o0 + q4 * 4 + r];
#pragma unroll
            for (int nt = 0; nt < 4; ++nt) {
                f32x4 acc = {0.f, 0.f, 0.f, 0.f};
#pragma unroll
                for (int ks = 0; ks < 4; ++ks)
                    acc = MFMA_BF16(af[ks], bfrag[nt][ks], acc);
                int n = n0 + nt * 16 + l15;
                unsigned int lo = (unsigned int)f2bf(acc[0] + bias[0]) |
                                  ((unsigned int)f2bf(acc[1] + bias[1]) << 16);
                unsigned int hi = (unsigned int)f2bf(acc[2] + bias[2]) |
                                  ((unsigned int)f2bf(acc[3] + bias[3]) << 16);
                uint2 pk; pk.x = lo; pk.y = hi;
                *(uint2*)&k_ws[((size_t)(b * 4096 + n) << 7) + o0 + q4 * 4] = pk;
            }
        } else {                      // V transposed: D[row=n(reg)][col=c=l15] -> vstage
            int c = o0 - 128 + l15;
            float vb = qkv_b[128 + o0 + l15];
#pragma unroll
            for (int nt = 0; nt < 4; ++nt) {
                f32x4 acc = {0.f, 0.f, 0.f, 0.f};
#pragma unroll
                for (int ks = 0; ks < 4; ++ks)
                    acc = MFMA_BF16(bfrag[nt][ks], af[ks], acc);
                unsigned int lo = (unsigned int)f2bf(acc[0] + vb) |
                                  ((unsigned int)f2bf(acc[1] + vb) << 16);
                unsigned int hi = (unsigned int)f2bf(acc[2] + vb) |
                                  ((unsigned int)f2bf(acc[3] + vb) << 16);
                uint2 pk; pk.x = lo; pk.y = hi;
                *(uint2*)&vstage[c * 72 + nt * 16 + q4 * 4] = pk;
            }
        }
    }
    __syncthreads();                  // vstage complete

    // cooperative V write: thread t -> row c = t>>1, 32-n half = t&1 -> 64 B contig
    {
        int c = tid >> 1, hf = tid & 1;
        const unsigned short* src = vstage + c * 72 + hf * 32;
        unsigned short* dst = v_ws + ((size_t)(b * 128 + c) << 12) + n0 + hf * 32;
        uint4 a0 = *(const uint4*)(src + 0);
        uint4 a1 = *(const uint4*)(src + 8);
        uint4 a2 = *(const uint4*)(src + 16);
        uint4 a3 = *(const uint4*)(src + 24);
        *(uint4*)(dst + 0)  = a0;
        *(uint4*)(dst + 8)  = a1;
        *(uint4*)(dst + 16) = a2;
        *(uint4*)(dst + 24) = a3;
    }
}

// ---------------- Kernel 3: FUSED GN+Q GEMM + flash attention + proj + residual ----
// grid = 256 blocks (b = blockIdx&7), 512 threads. Prologue computes Q for the
// block's 128 i-rows: sums->ms, h->O_lds, Wq GEMM -> Q staged in K0/K1, qf
// from LDS. Then main loop = R21/R23 (byte-identical; no setprio per R22).
__global__ __launch_bounds__(512, 2) void k_attn(const float* __restrict__ sums,
                                                 const float* __restrict__ gn_w,
                                                 const float* __restrict__ gn_b,
                                                 const unsigned short* __restrict__ wq,
                                                 const float* __restrict__ qkv_b,
                                                 const unsigned short* __restrict__ k_ws,
                                                 const unsigned short* __restrict__ v_ws,
                                                 const float* __restrict__ x,
                                                 const unsigned short* __restrict__ wp,
                                                 const float* __restrict__ proj_b,
                                                 float* __restrict__ out) {
    __shared__ unsigned short K0[64][128];      // 16 KB (prologue: Q rows 0..63)
    __shared__ unsigned short K1[64][128];      // 16 KB (prologue: Q rows 64..127)
    __shared__ unsigned short V0[128][64];      // 16 KB
    __shared__ unsigned short V1[128][64];      // 16 KB
    __shared__ unsigned short O_lds[128][136];  // 34 KB (prologue: h; epilogue: O)
    __shared__ float Lp[256];                   // 1 KB
    __shared__ float ms[8][2];                  // 64 B   -> ~100 KiB total

    const int tid   = threadIdx.x;              // 0..511
    const int b     = blockIdx.x & 7;           // batch -> same XCD for same b
    const int tile  = blockIdx.x >> 3;          // 0..31
    const int i0    = tile << 7;                // 128-row i-tile
    const int lane  = tid & 63, wave = tid >> 6;
    const int ih    = wave >> 1, jh = wave & 1;
    const int l31   = lane & 31, h = lane >> 5;
    const int irow  = ih * 32 + l31;

    // ---- prologue A: group stats ----
    if (tid < 8) {
        float s = 0.f, q = 0.f;
        const float* sp = sums + (size_t)(b * 8 + tid) * 32;
#pragma unroll
        for (int i = 0; i < 16; ++i) { s += sp[i * 2]; q += sp[i * 2 + 1]; }
        float mean = s * (1.f / 65536.f);
        float var  = q * (1.f / 65536.f) - mean * mean;
        ms[tid][0] = mean;
        ms[tid][1] = rsqrtf(var + 1e-5f);
    }
    __syncthreads();

    // ---- prologue B: h = GN(x) for rows i0..i0+127 -> O_lds[i_local][c] ----
    {
        int c = tid >> 2, qq = tid & 3;          // 128 c x 4 i-quarters
        float mean = ms[c >> 4][0], rstd = ms[c >> 4][1];
        float ga = gn_w[c] * rstd;
        float be = gn_b[c] - mean * ga;
        const float* xp = x + ((size_t)(b * 128 + c) << 12) + i0 + qq * 32;
#pragma unroll
        for (int k = 0; k < 8; ++k) {
            float4 v = *(const float4*)(xp + k * 4);
            int il = qq * 32 + k * 4;
            O_lds[il + 0][c] = f2bf(v.x * ga + be);
            O_lds[il + 1][c] = f2bf(v.y * ga + be);
            O_lds[il + 2][c] = f2bf(v.z * ga + be);
            O_lds[il + 3][c] = f2bf(v.w * ga + be);
        }
    }
    __syncthreads();

    // ---- prologue C: Q = Wq h + b (pre-scaled) -> K0/K1 as Q_lds[128][128] ----
    {
        const int l15 = lane & 15, q4 = lane >> 4;
        int o0q = wave * 16;                     // 8 waves x 16 o = 128
        short8 af[4];
#pragma unroll
        for (int ks = 0; ks < 4; ++ks)
            af[ks] = ldg8(wq + (size_t)(o0q + l15) * 128 + ks * 32 + q4 * 8);
        float qb[4];
#pragma unroll
        for (int r = 0; r < 4; ++r) qb[r] = qkv_b[o0q + q4 * 4 + r];
#pragma unroll
        for (int nt = 0; nt < 8; ++nt) {         // D[row=o(reg)][col=n=l15]
            f32x4 qacc = {0.f, 0.f, 0.f, 0.f};
#pragma unroll
            for (int ks = 0; ks < 4; ++ks) {
                short8 bf = *(const short8*)&O_lds[nt * 16 + l15][ks * 32 + q4 * 8];
                qacc = MFMA_BF16(af[ks], bf, qacc);
            }
            unsigned int lo = (unsigned int)f2bf((qacc[0] + qb[0]) * QSCALE) |
                              ((unsigned int)f2bf((qacc[1] + qb[1]) * QSCALE) << 16);
            unsigned int hi = (unsigned int)f2bf((qacc[2] + qb[2]) * QSCALE) |
                              ((unsigned int)f2bf((qacc[3] + qb[3]) * QSCALE) << 16);
            uint2 pk; pk.x = lo; pk.y = hi;
            unsigned short* qrow = (nt < 4) ? &K0[nt * 16 + l15][0]
                                            : &K1[(nt - 4) * 16 + l15][0];
            *(uint2*)(qrow + o0q + q4 * 4) = pk;
        }
    }
    __syncthreads();

    // ---- prologue D: qf from Q_lds; then release K0/K1 for staging ----
    short8 qf[8];
    {
        const unsigned short* qrow = (ih < 2) ? &K0[irow][0] : &K1[irow - 64][0];
#pragma unroll
        for (int ks = 0; ks < 8; ++ks)
            qf[ks] = *(const short8*)(qrow + ks * 16 + h * 8);
    }
    __syncthreads();                             // all qf reads done before STAGE(0)

    f32x16 acc[4];                           // O[i(reg)][c = ct*32 + l31], FULL C
#pragma unroll
    for (int ct = 0; ct < 4; ++ct)
#pragma unroll
        for (int e = 0; e < 16; ++e) acc[ct][e] = 0.f;
    float l_run = 0.f;

    // K staging: chunk c = q*512 + tid; dest linear; src slot = (c&15)^(row&15)
    const unsigned short* kbase = k_ws + ((size_t)b << 19);
    int ksrc[2];
#pragma unroll
    for (int q = 0; q < 2; ++q) {
        int c   = q * 512 + tid;
        int row = c >> 4;
        ksrc[q] = row * 16 + ((c & 15) ^ (row & 15));
    }
    // V staging: chunk c = q*512 + tid; row = c>>3 = q*64 + (tid>>3);
    // src s8 = (c&7) ^ key(row), key(row) = ((tid>>3)&7) ^ wave
    const unsigned short* vlane = v_ws + ((size_t)b << 19) +
        ((size_t)(tid >> 3) << 12) +
        ((((tid & 7) ^ ((tid >> 3) & 7) ^ wave)) << 3);

#define STAGE(T, KD, VD)                                                              \
  do {                                                                                \
    _Pragma("unroll")                                                                 \
    for (int q = 0; q < 2; ++q)                                                       \
      gload16(kbase + (size_t)(T) * 8192 + ksrc[q] * 8,                               \
              (char*)(&KD[0][0]) + q * 8192 + wave * 1024);                           \
    _Pragma("unroll")                                                                 \
    for (int q = 0; q < 2; ++q)                                                       \
      gload16(vlane + (size_t)q * 262144 + (T) * 64,                                  \
              (char*)(&VD[0][0]) + q * 8192 + wave * 1024);                           \
  } while (0)

// BAR_A: buf(t) DMA (issued 1 iter ago) visible -> vmcnt(0) only; prior LDS
// reads were consumed by MFMAs (WAR safe). sched_barrier: rule #18.
#define BAR_A()                                                                       \
  do {                                                                                \
    asm volatile("s_waitcnt vmcnt(0)" ::: "memory");                                  \
    __builtin_amdgcn_s_barrier();                                                     \
    __builtin_amdgcn_sched_barrier(0);                                                \
  } while (0)

    const int krow = jh * 32 + l31;
    const int ksw  = l31 & 15;                    // krow & 15
    const int vk   = (l31 & 7) ^ (l31 >> 3);      // V key base (^ ((ct&1)<<2) per ct)

    // prologue: prefetch tile 0 -> buf0 (drained at first BAR_A)
    STAGE(0, K0, V0);

#define ATTN_ITER(IT, KR, VR, KP, VP)                                                 \
  do {                                                                                \
    BAR_A(); /* buf visible; all waves' LDS reads consumed */                         \
    if ((IT) < 63) STAGE((IT) + 1, KP, VP);   /* in flight until next BAR_A */        \
    f32x16 s; /* S^T quadrant: row j=(r&3)+8(r>>2)+4h (+jh*32), col i (lane) */       \
    _Pragma("unroll")                                                                 \
    for (int e = 0; e < 16; ++e) s[e] = 0.f;                                          \
    _Pragma("unroll")                                                                 \
    for (int ks = 0; ks < 8; ++ks) {                                                  \
      short8 kf = *(const short8*)&KR[krow][((ks * 2 + h) ^ ksw) << 3];               \
      s = MFMA32(kf, qf[ks], s);                                                      \
    }                                                                                 \
    float pvv[16]; /* max-free base-2 softmax, in registers */                        \
    _Pragma("unroll")                                                                 \
    for (int e = 0; e < 16; ++e) pvv[e] = EXP2(fminf(s[e], 30.f));                    \
    l_run += (((pvv[0] + pvv[1]) + (pvv[2] + pvv[3])) +                               \
              ((pvv[4] + pvv[5]) + (pvv[6] + pvv[7]))) +                              \
             (((pvv[8] + pvv[9]) + (pvv[10] + pvv[11])) +                             \
              ((pvv[12] + pvv[13]) + (pvv[14] + pvv[15])));                           \
    short8 paf[2]; /* PV A-frag: lane m=i, k = j(in-quadrant) = ks*16 + h*8 + e */    \
    _Pragma("unroll")                                                                 \
    for (int ks = 0; ks < 2; ++ks) {                                                  \
      const float* pp = pvv + ks * 8;                                                 \
      unsigned int Wa = cvtpk(pp[0], pp[1]);                                          \
      unsigned int Wc = cvtpk(pp[2], pp[3]);                                          \
      unsigned int Wb = cvtpk(pp[4], pp[5]);                                          \
      unsigned int Wd = cvtpk(pp[6], pp[7]);                                          \
      auto r1 = __builtin_amdgcn_permlane32_swap(Wa, Wb, false, false);               \
      auto r2 = __builtin_amdgcn_permlane32_swap(Wc, Wd, false, false);               \
      uint4 aw; aw.x = r1[0]; aw.y = r2[0]; aw.z = r1[1]; aw.w = r2[1];               \
      paf[ks] = __builtin_bit_cast(short8, aw);   /* verified R2/R11/R20 */           \
    }                                                                                 \
    _Pragma("unroll")                                                                 \
    for (int ks = 0; ks < 2; ++ks)                                                    \
      _Pragma("unroll")                                                               \
      for (int ct = 0; ct < 4; ++ct) {                                                \
        short8 vf = *(const short8*)&VR[ct * 32 + l31]                                \
            [((jh * 4 + ks * 2 + h) ^ vk ^ ((ct & 1) << 2)) << 3];                    \
        acc[ct] = MFMA32(paf[ks], vf, acc[ct]);                                       \
      }                                                                               \
  } while (0)

    for (int ib = 0; ib < 32; ++ib) {
        int it = ib * 2;
        ATTN_ITER(it,     K0, V0, K1, V1);
        ATTN_ITER(it + 1, K1, V1, K0, V0);
    }
#undef ATTN_ITER
#undef STAGE
#undef BAR_A

    // ---- epilogue 1: jh-pair O reduce (overlay deposit in K/V bufs, f32) ----
    __syncthreads();                                 // full drain before overlay
    float l2 = l_run + __shfl_xor(l_run, 32);        // h-halves: disjoint j, same i
    if (h == 0) Lp[jh * 128 + irow] = l2;
    float* ObLow  = (ih < 2) ? (float*)&K0[0][0] : (float*)&K1[0][0];
    float* ObHigh = (ih < 2) ? (float*)&V0[0][0] : (float*)&V1[0][0];
    const int vbase = (ih & 1) * 32;                 // row offset within half-array
    if (jh) {                                        // deposit LOW c (acc[0,1])
#pragma unroll
        for (int cc = 0; cc < 2; ++cc)
#pragma unroll
            for (int r = 0; r < 16; ++r) {
                int il = (r & 3) + ((r >> 2) << 3) + (h << 2);
                ObLow[(vbase + il) * 64 + cc * 32 + l31] = (cc == 0) ? acc[0][r] : acc[1][r];
            }
    } else {                                         // deposit HIGH c (acc[2,3])
#pragma unroll
        for (int cc = 0; cc < 2; ++cc)
#pragma unroll
            for (int r = 0; r < 16; ++r) {
                int il = (r & 3) + ((r >> 2) << 3) + (h << 2);
                ObHigh[(vbase + il) * 64 + cc * 32 + l31] = (cc == 0) ? acc[2][r] : acc[3][r];
            }
    }
    __syncthreads();
    // ---- epilogue 2: normalize + write bf16 O to O_lds ----
    {
        float rl[16];
#pragma unroll
        for (int r = 0; r < 16; ++r) {
            int il = (r & 3) + ((r >> 2) << 3) + (h << 2);
            rl[r] = 1.0f / (Lp[ih * 32 + il] + Lp[128 + ih * 32 + il]);
        }
        if (jh) {                                    // finalize HIGH c: own acc[2,3]+ObHigh
#pragma unroll
            for (int cc = 0; cc < 2; ++cc)
#pragma unroll
                for (int r = 0; r < 16; ++r) {
                    int il = (r & 3) + ((r >> 2) << 3) + (h << 2);
                    float own = (cc == 0) ? acc[2][r] : acc[3][r];
                    float v = own + ObHigh[(vbase + il) * 64 + cc * 32 + l31];
                    O_lds[ih * 32 + il][64 + cc * 32 + l31] = f2bf(v * rl[r]);
                }
        } else {                                     // finalize LOW c: own acc[0,1]+ObLow
#pragma unroll
            for (int cc = 0; cc < 2; ++cc)
#pragma unroll
                for (int r = 0; r < 16; ++r) {
                    int il = (r & 3) + ((r >> 2) << 3) + (h << 2);
                    float own = (cc == 0) ? acc[0][r] : acc[1][r];
                    float v = own + ObLow[(vbase + il) * 64 + cc * 32 + l31];
                    O_lds[ih * 32 + il][cc * 32 + l31] = f2bf(v * rl[r]);
                }
        }
    }
    __syncthreads();

    // ---- epilogue 3: proj GEMM + bias + residual ----
    // out[o][n] = sum_c proj_w[o][c] * O[n][c] + proj_b[o] + x[o][n]
    {
        const int l15 = lane & 15, q4 = lane >> 4;
        int o0 = wave * 16;                          // 8 waves x 16 o-rows = 128
        short8 af[4];
#pragma unroll
        for (int ks = 0; ks < 4; ++ks)
            af[ks] = ldg8(wp + (size_t)(o0 + l15) * 128 + ks * 32 + q4 * 8);
        float pb[4];
#pragma unroll
        for (int r = 0; r < 4; ++r) pb[r] = proj_b[o0 + q4 * 4 + r];

#pragma unroll
        for (int nt = 0; nt < 8; ++nt) {             // 8 x 16 = 128 n-rows
            f32x4 pacc = {0.f, 0.f, 0.f, 0.f};
#pragma unroll
            for (int ks = 0; ks < 4; ++ks) {
                short8 bf = *(const short8*)&O_lds[nt * 16 + l15][ks * 32 + q4 * 8];
                pacc = MFMA_BF16(af[ks], bf, pacc);
            }
#pragma unroll
            for (int r = 0; r < 4; ++r) {
                size_t idx = ((size_t)(b * 128 + o0 + q4 * 4 + r) << 12) +
                             i0 + nt * 16 + l15;
                out[idx] = x[idx] + pacc[r] + pb[r];
            }
        }
    }
}

// ---------------- launch ----------------
extern "C" void kernel_launch(void* const* d_in, const int* in_sizes, int n_in,
                              void* d_out, int out_size, void* d_ws, size_t ws_size,
                              hipStream_t stream) {
    const float* x      = (const float*)d_in[0];
    const float* gn_w   = (const float*)d_in[1];
    const float* gn_b   = (const float*)d_in[2];
    const float* qkv_w  = (const float*)d_in[3];
    const float* qkv_b  = (const float*)d_in[4];
    const float* proj_w = (const float*)d_in[5];
    const float* proj_b = (const float*)d_in[6];
    float* out = (float*)d_out;

    char* ws = (char*)d_ws;
    float* sums           = (float*)ws;                              // 8 KB partials (no init)
    unsigned short* wq    = (unsigned short*)(ws + 16384);           // 96 KB (Wq|Wk|Wv)
    unsigned short* wp    = (unsigned short*)(ws + 16384 + 98304);   // 32 KB
    unsigned short* k_ws  = (unsigned short*)(ws + ((size_t)1 << 20));   // 8 MB
    unsigned short* v_ws  = (unsigned short*)(ws + ((size_t)9 << 20));   // 8 MB

    k_pre<<<1088, 256, 0, stream>>>(x, sums, qkv_w, proj_w, wq, wp);
    k_qkv<<<512, 256, 0, stream>>>(x, sums, gn_w, gn_b, wq, qkv_b, k_ws, v_ws);
    k_attn<<<256, 512, 0, stream>>>(sums, gn_w, gn_b, wq, qkv_b, k_ws, v_ws,
                                    x, wp, proj_b, out);
}